// Round 4
// baseline (15516.338 us; speedup 1.0000x reference)
//
#include <hip/hip_runtime.h>
#include <stdint.h>
#include <stddef.h>

// LSTM 2-layer, B=64,T=1024,D=64,H=256 -> fc(mean_t h)  [MI355X gfx950]
// R4: scan = 4 WGs x 256 thr (4 waves, 1 wave/SIMD, 512-reg budget via
// amdgpu_waves_per_eu(1,1)). Per-CU capacity math: weights 512KB must split
// 360 VGPRs/wave (90 frags) + 152KB LDS (38 frags/wave); h single-buffer 8KB
// -> LDS = 163840 exactly. Two gate-passes per step (i,f then g,o) keep the
// working set ~150 regs. 1024-thr (R3) capped regs at 128 -> mass spill;
// 512-thr (R1) needed ~300 vs 256 budget -> spill. This config fits.

#define T_LEN 1024
#define NB    64
#define DIN   64
#define HID   256
#define G4    1024
#define CH    256
#define NCH   (T_LEN/CH)

typedef __attribute__((ext_vector_type(8))) short  bf16x8;
typedef __attribute__((ext_vector_type(4))) float  f32x4;

__device__ __forceinline__ ushort f2b(float x) {      // fp32 -> bf16 RNE
  uint u = __float_as_uint(x);
  uint r = (u + 0x7fffu + ((u >> 16) & 1u)) >> 16;
  return (ushort)r;
}
__device__ __forceinline__ float b2f(uint u16) {      // bf16 -> fp32 exact
  return __uint_as_float(u16 << 16);
}
__device__ __forceinline__ float sigm(float x) {
  float e = __expf(-x);
  return __builtin_amdgcn_rcpf(1.f + e);
}
__device__ __forceinline__ float tanhf_fast(float x) {
  float e = __expf(-2.f * x);
  return (1.f - e) * __builtin_amdgcn_rcpf(1.f + e);
}

// ---------------- weight convert (fp32->bf16) + bias sums -----------------
__global__ void convert_weights(const float* __restrict__ Wih0, const float* __restrict__ Whh0,
                                const float* __restrict__ Wih1, const float* __restrict__ Whh1,
                                const float* __restrict__ bih0, const float* __restrict__ bhh0,
                                const float* __restrict__ bih1, const float* __restrict__ bhh1,
                                ushort* __restrict__ Wb, float* __restrict__ bsum)
{
  int i = blockIdx.x * 256 + threadIdx.x;
  const int n0 = G4*DIN, n1 = G4*HID;
  const int total = n0 + 3*n1;                 // 851968
  if (i < total) {
    float v;
    if (i < n0)           v = Wih0[i];
    else if (i < n0+n1)   v = Whh0[i-n0];
    else if (i < n0+2*n1) v = Wih1[i-n0-n1];
    else                  v = Whh1[i-n0-2*n1];
    Wb[i] = f2b(v);
  }
  if (i < G4)        bsum[i] = bih0[i] + bhh0[i];
  else if (i < 2*G4) bsum[i] = bih1[i-G4] + bhh1[i-G4];
}

// ------------- input-projection GEMM: gx[t] = A_t @ W^T + bias -------------
// SRC=0: A = x fp32 [B][T][DIN]  (KDIM=64)
// SRC=1: A = hs0c bf16 [CH][64][HID] (KDIM=256)
// grid (CH, 2): blockIdx.y picks 2 of the 4 m-tiles (acc = 64 VGPRs, no spill)
// Output gxF bf16 in MFMA-fragment order: [tloc][ct 0..63][grp 0..3][lane][r]
template<int SRC, int KDIM>
__global__ __launch_bounds__(512) void gemm_gates(
    const void* __restrict__ Asrc, const ushort* __restrict__ W,
    const float* __restrict__ bias, ushort* __restrict__ gxF, int t0)
{
  __shared__ __align__(16) char sA[64 * KDIM * 2];
  const int tid  = threadIdx.x;
  const int wave = tid >> 6, lane = tid & 63;
  const int l15 = lane & 15, lhi = lane >> 4;
  const int tloc = blockIdx.x;
  const int mt0 = blockIdx.y * 2;
  const int t = t0 + tloc;

  if (SRC == 0) {
    const float* x = (const float*)Asrc;
    int b = tid >> 3, k8 = (tid & 7) * 8;
    const float* xp = x + ((size_t)b * T_LEN + t) * DIN + k8;
    float4 v0 = *(const float4*)xp;
    float4 v1 = *(const float4*)(xp + 4);
    bf16x8 pv;
    pv[0]=(short)f2b(v0.x); pv[1]=(short)f2b(v0.y); pv[2]=(short)f2b(v0.z); pv[3]=(short)f2b(v0.w);
    pv[4]=(short)f2b(v1.x); pv[5]=(short)f2b(v1.y); pv[6]=(short)f2b(v1.z); pv[7]=(short)f2b(v1.w);
    uint bo = (uint)(b * KDIM * 2 + k8 * 2) ^ ((uint)(b & 7) << 4);
    *reinterpret_cast<bf16x8*>(&sA[bo]) = pv;
  } else {
    const ushort* hs = (const ushort*)Asrc;
    int b = tid >> 3, kb = tid & 7;
    #pragma unroll
    for (int j = 0; j < KDIM/64; ++j) {
      int k8 = (kb + j*8) * 8;
      bf16x8 v = *reinterpret_cast<const bf16x8*>(hs + ((size_t)tloc * 64 + b) * KDIM + k8);
      uint bo = (uint)(b * KDIM * 2 + k8 * 2) ^ ((uint)(b & 7) << 4);
      *reinterpret_cast<bf16x8*>(&sA[bo]) = v;
    }
  }
  __syncthreads();

  float bb[8];
  #pragma unroll
  for (int i = 0; i < 8; ++i) bb[i] = bias[(wave*8 + i)*16 + l15];

  f32x4 acc[2][8];
  #pragma unroll
  for (int m = 0; m < 2; ++m)
    #pragma unroll
    for (int i = 0; i < 8; ++i) {
      acc[m][i][0] = bb[i]; acc[m][i][1] = bb[i];
      acc[m][i][2] = bb[i]; acc[m][i][3] = bb[i];
    }

  #pragma unroll
  for (int kc = 0; kc < KDIM/32; ++kc) {
    const int koff = kc*32 + lhi*8;
    bf16x8 wf[8];
    #pragma unroll
    for (int i = 0; i < 8; ++i)
      wf[i] = *reinterpret_cast<const bf16x8*>(W + (size_t)((wave*8 + i)*16 + l15) * KDIM + koff);
    #pragma unroll
    for (int m = 0; m < 2; ++m) {
      const int row = (mt0 + m)*16 + l15;
      const uint bo = (uint)(row * KDIM * 2 + koff * 2) ^ ((uint)(row & 7) << 4);
      bf16x8 a = *reinterpret_cast<const bf16x8*>(&sA[bo]);
      #pragma unroll
      for (int i = 0; i < 8; ++i)
        acc[m][i] = __builtin_amdgcn_mfma_f32_16x16x32_bf16(a, wf[i], acc[m][i], 0, 0, 0);
    }
  }

  #pragma unroll
  for (int m = 0; m < 2; ++m)
    #pragma unroll
    for (int i = 0; i < 8; ++i) {
      const int ct = wave*8 + i;
      uint2 q;
      q.x = (uint)f2b(acc[m][i][0]) | ((uint)f2b(acc[m][i][1]) << 16);
      q.y = (uint)f2b(acc[m][i][2]) | ((uint)f2b(acc[m][i][3]) << 16);
      *reinterpret_cast<uint2*>(gxF + ((size_t)((tloc*64 + ct)*4 + (mt0+m))*64 + lane)*4) = q;
    }
}

// --------------------------- recurrent scan -------------------------------
// 4 WGs x 256 thr (4 waves, 1/SIMD). Wave w owns hidden units [64w,64w+64)
// x 4 gates = 16 col-tiles t=g*4+j (cols g*256 + w*64 + j*16). Frag (t,kc):
// LDS if kc>=6 or (kc==5 && t>=10) [38/wave, 152KB total]; else VGPR [90/wave,
// 360 regs]. Two passes per step: gates i,f then g,o (acc 32 regs/pass).
// h single-buffered in LDS (8KB, XOR-swizzled), 2 barriers/step.
template<int LAYER>
__global__ __launch_bounds__(256)
__attribute__((amdgpu_waves_per_eu(1, 1)))
void lstm_scan(
    const ushort* __restrict__ gxF, const ushort* __restrict__ Whh,
    ushort* __restrict__ hs_out,     // LAYER0: [CH][64][256] bf16
    float* __restrict__ hsum_out,    // LAYER1: [64][256]
    ushort* __restrict__ h_state,    // [4][4096] ushort (raw swizzled 8KB/grp)
    float* __restrict__ c_state,     // [4][256][16]
    float* __restrict__ hacc_state,  // LAYER1: [4][256][16]
    int t0)
{
  __shared__ __align__(16) char sW[155648];   // [4 waves][38 frags][1024B]
  __shared__ __align__(16) char sH[8192];     // h (single buffer, swizzled)

  const int tid = threadIdx.x;
  const int wave = tid >> 6, lane = tid & 63;
  const int l15 = lane & 15, lhi = lane >> 4;
  const int grp = blockIdx.x;

  // ---- load weights: VGPR majority + LDS overflow (once) ----
  bf16x8 wv[16][8];                            // ~90 entries live post-SROA
  #pragma unroll
  for (int t = 0; t < 16; ++t) {
    const int g = t >> 2, j = t & 3;
    const ushort* wp = Whh + (size_t)(g*256 + wave*64 + j*16 + l15) * HID;
    #pragma unroll
    for (int kc = 0; kc < 8; ++kc) {
      bf16x8 w = *reinterpret_cast<const bf16x8*>(wp + kc*32 + lhi*8);
      if ((kc >= 6) || (kc == 5 && t >= 10)) {
        const int fid = (kc == 6) ? t : (kc == 7) ? (16 + t) : (32 + (t - 10));
        *reinterpret_cast<bf16x8*>(&sW[((wave*38 + fid) << 10) + lane*16]) = w;
      } else {
        wv[t][kc] = w;
      }
    }
  }

  // ---- init / restore h in LDS ----
  if (t0 == 0) {
    for (int i = tid; i < 2048; i += 256) reinterpret_cast<uint*>(sH)[i] = 0u;
  } else {
    const uint* src = reinterpret_cast<const uint*>(h_state) + grp*2048;
    for (int i = tid; i < 2048; i += 256) reinterpret_cast<uint*>(sH)[i] = src[i];
  }

  float c[16], hacc[16];
  if (t0 == 0) {
    #pragma unroll
    for (int i = 0; i < 16; ++i) { c[i] = 0.f; hacc[i] = 0.f; }
  } else {
    const float* cs = c_state + ((size_t)grp*256 + tid)*16;
    #pragma unroll
    for (int i = 0; i < 16; ++i) c[i] = cs[i];
    if (LAYER == 1) {
      const float* ha = hacc_state + ((size_t)grp*256 + tid)*16;
      #pragma unroll
      for (int i = 0; i < 16; ++i) hacc[i] = ha[i];
    } else {
      #pragma unroll
      for (int i = 0; i < 16; ++i) hacc[i] = 0.f;
    }
  }

  // gx fragment address for tile t at local step tl
  // ct(t) = (t>>2)*16 + wave*4 + (t&3)
  #define GX_LD(tl, t) (*reinterpret_cast<const uint2*>( \
      gxF + ((size_t)(((tl)*64 + ((t)>>2)*16 + wave*4 + ((t)&3))*4 + grp)*64 + lane)*4))

  // A-fragment (old h) read, swizzle matches writer
  #define LD_A(kc) (*reinterpret_cast<const bf16x8*>(&sH[ \
      (uint)(l15*512 + ((kc)*32 + lhi*8)*2) ^ ((uint)(l15 & 7) << 4)]))

  // weight fragment for (t,kc) — LDS or VGPR, folded at compile time
  #define LD_W(t, kc) (((kc) >= 6 || ((kc) == 5 && (t) >= 10)) ? \
      *reinterpret_cast<const bf16x8*>(&sW[((wave*38 + \
        ((kc) == 6 ? (t) : (kc) == 7 ? (16 + (t)) : (32 + ((t) - 10)))) << 10) + lane*16]) \
      : wv[t][kc])

  // ---- prefetch gx for step 0, pass 0 (tiles 0..7) ----
  uint2 gxb[8];
  #pragma unroll
  for (int t2 = 0; t2 < 8; ++t2) gxb[t2] = GX_LD(0, t2);

  __syncthreads();

  #pragma unroll 1
  for (int tloc = 0; tloc < CH; ++tloc) {
    // ================= pass 0: gates i (t 0..3), f (t 4..7) =================
    f32x4 acc0[4], acc1[4];
    #pragma unroll
    for (int j = 0; j < 4; ++j) {
      uint2 qi = gxb[j], qf = gxb[4 + j];
      acc0[j][0] = b2f(qi.x & 0xffffu); acc0[j][1] = b2f(qi.x >> 16);
      acc0[j][2] = b2f(qi.y & 0xffffu); acc0[j][3] = b2f(qi.y >> 16);
      acc1[j][0] = b2f(qf.x & 0xffffu); acc1[j][1] = b2f(qf.x >> 16);
      acc1[j][2] = b2f(qf.y & 0xffffu); acc1[j][3] = b2f(qf.y >> 16);
    }
    // issue pass-1 gx loads (tiles 8..15, same step) — covered by pass-0 work
    #pragma unroll
    for (int t2 = 0; t2 < 8; ++t2) gxb[t2] = GX_LD(tloc, 8 + t2);

    #pragma unroll
    for (int kc = 0; kc < 8; ++kc) {
      bf16x8 a = LD_A(kc);
      #pragma unroll
      for (int j = 0; j < 4; ++j) {
        acc0[j] = __builtin_amdgcn_mfma_f32_16x16x32_bf16(a, LD_W(j,     kc), acc0[j], 0, 0, 0);
        acc1[j] = __builtin_amdgcn_mfma_f32_16x16x32_bf16(a, LD_W(4 + j, kc), acc1[j], 0, 0, 0);
      }
    }

    float ii[16], tv[16];
    #pragma unroll
    for (int j = 0; j < 4; ++j)
      #pragma unroll
      for (int r = 0; r < 4; ++r) {
        const int idx = j*4 + r;
        ii[idx] = sigm(acc0[j][r]);
        tv[idx] = sigm(acc1[j][r]) * c[idx];     // f*c_old
      }

    // ================= pass 1: gates g (t 8..11), o (t 12..15) ==============
    #pragma unroll
    for (int j = 0; j < 4; ++j) {
      uint2 qg = gxb[j], qo = gxb[4 + j];
      acc0[j][0] = b2f(qg.x & 0xffffu); acc0[j][1] = b2f(qg.x >> 16);
      acc0[j][2] = b2f(qg.y & 0xffffu); acc0[j][3] = b2f(qg.y >> 16);
      acc1[j][0] = b2f(qo.x & 0xffffu); acc1[j][1] = b2f(qo.x >> 16);
      acc1[j][2] = b2f(qo.y & 0xffffu); acc1[j][3] = b2f(qo.y >> 16);
    }
    // issue next-step pass-0 gx loads — covered by pass-1 work
    {
      const int tln = (tloc + 1) & (CH - 1);
      #pragma unroll
      for (int t2 = 0; t2 < 8; ++t2) gxb[t2] = GX_LD(tln, t2);
    }

    #pragma unroll
    for (int kc = 0; kc < 8; ++kc) {
      bf16x8 a = LD_A(kc);
      #pragma unroll
      for (int j = 0; j < 4; ++j) {
        acc0[j] = __builtin_amdgcn_mfma_f32_16x16x32_bf16(a, LD_W(8 + j,  kc), acc0[j], 0, 0, 0);
        acc1[j] = __builtin_amdgcn_mfma_f32_16x16x32_bf16(a, LD_W(12 + j, kc), acc1[j], 0, 0, 0);
      }
    }

    __syncthreads();             // barrier 1: all reads of old h complete

    #pragma unroll
    for (int j = 0; j < 4; ++j)
      #pragma unroll
      for (int r = 0; r < 4; ++r) {
        const int idx = j*4 + r;
        float gg = tanhf_fast(acc0[j][r]);
        float oo = sigm(acc1[j][r]);
        float cn = __builtin_fmaf(ii[idx], gg, tv[idx]);
        c[idx] = cn;
        float h = oo * tanhf_fast(cn);
        if (LAYER == 1) hacc[idx] += h;
        const int b = lhi*4 + r;
        const int u = wave*64 + j*16 + l15;
        const uint wb = (uint)(b*512 + u*2) ^ ((uint)(b & 7) << 4);
        *reinterpret_cast<ushort*>(&sH[wb]) = f2b(h);
        if (LAYER == 0)
          hs_out[((size_t)tloc*64 + grp*16 + b)*256 + u] = f2b(h);
      }

    __syncthreads();             // barrier 2: new h fully written
  }

  // ---- save state ----
  {
    uint* dst = reinterpret_cast<uint*>(h_state) + grp*2048;
    const uint* src = reinterpret_cast<const uint*>(sH);
    for (int i = tid; i < 2048; i += 256) dst[i] = src[i];
    float* cs = c_state + ((size_t)grp*256 + tid)*16;
    #pragma unroll
    for (int i = 0; i < 16; ++i) cs[i] = c[i];
    if (LAYER == 1) {
      float* ha = hacc_state + ((size_t)grp*256 + tid)*16;
      #pragma unroll
      for (int i = 0; i < 16; ++i) ha[i] = hacc[i];
      #pragma unroll
      for (int j = 0; j < 4; ++j)
        #pragma unroll
        for (int r = 0; r < 4; ++r) {
          const int b = lhi*4 + r;
          const int u = wave*64 + j*16 + l15;
          hsum_out[((size_t)grp*16 + b)*256 + u] = hacc[j*4 + r];
        }
    }
  }
  #undef GX_LD
  #undef LD_A
  #undef LD_W
}

// ------------------------------- final fc ---------------------------------
__global__ void fc_kernel(const float* __restrict__ hsum, const float* __restrict__ Wfc,
                          const float* __restrict__ bfc, float* __restrict__ out)
{
  int tid = threadIdx.x;
  if (tid < 640) {
    int b = tid / 10, o = tid - b*10;
    const float* hp = hsum + b*256;
    const float* wp = Wfc + o*256;
    float s = 0.f;
    #pragma unroll 8
    for (int u = 0; u < 256; ++u) s = __builtin_fmaf(hp[u], wp[u], s);
    out[tid] = s * (1.f/1024.f) + bfc[o];
  }
}

extern "C" void kernel_launch(void* const* d_in, const int* in_sizes, int n_in,
                              void* d_out, int out_size, void* d_ws, size_t ws_size,
                              hipStream_t stream)
{
  const float* x    = (const float*)d_in[0];
  const float* Wih0 = (const float*)d_in[1];
  const float* Whh0 = (const float*)d_in[2];
  const float* bih0 = (const float*)d_in[3];
  const float* bhh0 = (const float*)d_in[4];
  const float* Wih1 = (const float*)d_in[5];
  const float* Whh1 = (const float*)d_in[6];
  const float* bih1 = (const float*)d_in[7];
  const float* bhh1 = (const float*)d_in[8];
  const float* Wfc  = (const float*)d_in[9];
  const float* bfc  = (const float*)d_in[10];
  float* out = (float*)d_out;
  char* ws = (char*)d_ws;

  // ws layout (total ~44.6 MB)
  ushort* Wb    = (ushort*)(ws);                              // 1,703,936 B
  float*  bsum  = (float*)(ws + 1703936);                     // 8,192 B
  ushort* gxF   = (ushort*)(ws + 2097152);                    // 32 MB (chunk)
  ushort* hs0c  = (ushort*)(ws + 2097152 + 33554432);         // 8 MB (chunk)
  float*  hsum  = (float*)(ws + 2097152 + 33554432 + 8388608);// 64 KB
  char*   st    = ws + 2097152 + 33554432 + 8388608 + 65536;
  ushort* hst0  = (ushort*)(st);                              // 32 KB
  ushort* hst1  = (ushort*)(st + 32768);                      // 32 KB
  float*  cst0  = (float*)(st + 65536);                       // 64 KB
  float*  cst1  = (float*)(st + 131072);                      // 64 KB
  float*  hast  = (float*)(st + 196608);                      // 64 KB

  hipLaunchKernelGGL(convert_weights, dim3(3328), dim3(256), 0, stream,
                     Wih0, Whh0, Wih1, Whh1, bih0, bhh0, bih1, bhh1, Wb, bsum);

  const ushort* Whh0b = Wb + 65536;
  const ushort* Wih1b = Wb + 327680;
  const ushort* Whh1b = Wb + 589824;

  for (int cidx = 0; cidx < NCH; ++cidx) {
    int t0 = cidx * CH;
    hipLaunchKernelGGL((gemm_gates<0,64>), dim3(CH,2), dim3(512), 0, stream,
                       (const void*)x, Wb, bsum, gxF, t0);
    hipLaunchKernelGGL((lstm_scan<0>), dim3(4), dim3(256), 0, stream,
                       gxF, Whh0b, hs0c, (float*)nullptr, hst0, cst0, (float*)nullptr, t0);
    hipLaunchKernelGGL((gemm_gates<1,256>), dim3(CH,2), dim3(512), 0, stream,
                       (const void*)hs0c, Wih1b, bsum + 1024, gxF, t0);
    hipLaunchKernelGGL((lstm_scan<1>), dim3(4), dim3(256), 0, stream,
                       gxF, Whh1b, (ushort*)nullptr, hsum, hst1, cst1, hast, t0);
  }
  hipLaunchKernelGGL(fc_kernel, dim3(1), dim3(640), 0, stream, hsum, Wfc, bfc, out);
}

// Round 7
// 7484.235 us; speedup vs baseline: 2.0732x; 2.0732x over previous
//
#include <hip/hip_runtime.h>
#include <stdint.h>
#include <stddef.h>

// LSTM 2-layer, B=64,T=1024,D=64,H=256 -> fc(mean_t h)  [MI355X gfx950]
// R7: all-BUILTIN MFMAs (compiler handles every MFMA hazard). AGPR residency
// via placement bias only: one-time asm("":"+a") pin of 64 frags/wave
// (kc 0..3, 256 AGPR = file full at 1 wave/SIMD); kc 4..5 arch VGPR (128);
// kc 6..7 LDS (128KB). 4 passes/step (one gate each) cuts arch working set
// to ~100 regs -> ~232/256 arch, real allocator slack (R6 was ~250 -> live
// range splits -> VALU->MFMA hazard corruption with asm MFMA).
// Fused launch: scan0(c+1) || scan1(c). 256 thr/WG, amdgpu_waves_per_eu(1,1).

#define T_LEN 1024
#define NB    64
#define DIN   64
#define HID   256
#define G4    1024
#define CH    128
#define NCH   (T_LEN/CH)

typedef __attribute__((ext_vector_type(8))) short  bf16x8;
typedef __attribute__((ext_vector_type(4))) float  f32x4;

__device__ __forceinline__ ushort f2b(float x) {      // fp32 -> bf16 RNE
  uint u = __float_as_uint(x);
  uint r = (u + 0x7fffu + ((u >> 16) & 1u)) >> 16;
  return (ushort)r;
}
__device__ __forceinline__ float b2f(uint u16) {      // bf16 -> fp32 exact
  return __uint_as_float(u16 << 16);
}
__device__ __forceinline__ float sigm(float x) {
  float e = __expf(-x);
  return __builtin_amdgcn_rcpf(1.f + e);
}
__device__ __forceinline__ float tanhf_fast(float x) {
  x = fmaxf(-20.f, fminf(20.f, x));                   // exact for tanh, NaN-proof
  float e = __expf(-2.f * x);
  return (1.f - e) * __builtin_amdgcn_rcpf(1.f + e);
}

// ---------------- weight convert (fp32->bf16) + bias sums -----------------
__global__ void convert_weights(const float* __restrict__ Wih0, const float* __restrict__ Whh0,
                                const float* __restrict__ Wih1, const float* __restrict__ Whh1,
                                const float* __restrict__ bih0, const float* __restrict__ bhh0,
                                const float* __restrict__ bih1, const float* __restrict__ bhh1,
                                ushort* __restrict__ Wb, float* __restrict__ bsum)
{
  int i = blockIdx.x * 256 + threadIdx.x;
  const int n0 = G4*DIN, n1 = G4*HID;
  const int total = n0 + 3*n1;                 // 851968
  if (i < total) {
    float v;
    if (i < n0)           v = Wih0[i];
    else if (i < n0+n1)   v = Whh0[i-n0];
    else if (i < n0+2*n1) v = Wih1[i-n0-n1];
    else                  v = Whh1[i-n0-2*n1];
    Wb[i] = f2b(v);
  }
  if (i < G4)        bsum[i] = bih0[i] + bhh0[i];
  else if (i < 2*G4) bsum[i] = bih1[i-G4] + bhh1[i-G4];
}

// ------------- input-projection GEMM: gx[t] = A_t @ W^T + bias -------------
// SRC=0: A = x fp32 [B][T][DIN]  (KDIM=64)
// SRC=1: A = hs0 chunk bf16 [CH][64][HID] (KDIM=256)
// grid (CH, 2): blockIdx.y picks 2 of the 4 m-tiles.
// Output gxF bf16 in MFMA-fragment order: [tloc][ct 0..63][grp 0..3][lane][r]
template<int SRC, int KDIM>
__global__ __launch_bounds__(512) void gemm_gates(
    const void* __restrict__ Asrc, const ushort* __restrict__ W,
    const float* __restrict__ bias, ushort* __restrict__ gxF, int t0)
{
  __shared__ __align__(16) char sA[64 * KDIM * 2];
  const int tid  = threadIdx.x;
  const int wave = tid >> 6, lane = tid & 63;
  const int l15 = lane & 15, lhi = lane >> 4;
  const int tloc = blockIdx.x;
  const int mt0 = blockIdx.y * 2;
  const int t = t0 + tloc;

  if (SRC == 0) {
    const float* x = (const float*)Asrc;
    int b = tid >> 3, k8 = (tid & 7) * 8;
    const float* xp = x + ((size_t)b * T_LEN + t) * DIN + k8;
    float4 v0 = *(const float4*)xp;
    float4 v1 = *(const float4*)(xp + 4);
    bf16x8 pv;
    pv[0]=(short)f2b(v0.x); pv[1]=(short)f2b(v0.y); pv[2]=(short)f2b(v0.z); pv[3]=(short)f2b(v0.w);
    pv[4]=(short)f2b(v1.x); pv[5]=(short)f2b(v1.y); pv[6]=(short)f2b(v1.z); pv[7]=(short)f2b(v1.w);
    uint bo = (uint)(b * KDIM * 2 + k8 * 2) ^ ((uint)(b & 7) << 4);
    *reinterpret_cast<bf16x8*>(&sA[bo]) = pv;
  } else {
    const ushort* hs = (const ushort*)Asrc;
    int b = tid >> 3, kb = tid & 7;
    #pragma unroll
    for (int j = 0; j < KDIM/64; ++j) {
      int k8 = (kb + j*8) * 8;
      bf16x8 v = *reinterpret_cast<const bf16x8*>(hs + ((size_t)tloc * 64 + b) * KDIM + k8);
      uint bo = (uint)(b * KDIM * 2 + k8 * 2) ^ ((uint)(b & 7) << 4);
      *reinterpret_cast<bf16x8*>(&sA[bo]) = v;
    }
  }
  __syncthreads();

  float bb[8];
  #pragma unroll
  for (int i = 0; i < 8; ++i) bb[i] = bias[(wave*8 + i)*16 + l15];

  f32x4 acc[2][8];
  #pragma unroll
  for (int m = 0; m < 2; ++m)
    #pragma unroll
    for (int i = 0; i < 8; ++i) {
      acc[m][i][0] = bb[i]; acc[m][i][1] = bb[i];
      acc[m][i][2] = bb[i]; acc[m][i][3] = bb[i];
    }

  #pragma unroll
  for (int kc = 0; kc < KDIM/32; ++kc) {
    const int koff = kc*32 + lhi*8;
    bf16x8 wf[8];
    #pragma unroll
    for (int i = 0; i < 8; ++i)
      wf[i] = *reinterpret_cast<const bf16x8*>(W + (size_t)((wave*8 + i)*16 + l15) * KDIM + koff);
    #pragma unroll
    for (int m = 0; m < 2; ++m) {
      const int row = (mt0 + m)*16 + l15;
      const uint bo = (uint)(row * KDIM * 2 + koff * 2) ^ ((uint)(row & 7) << 4);
      bf16x8 a = *reinterpret_cast<const bf16x8*>(&sA[bo]);
      #pragma unroll
      for (int i = 0; i < 8; ++i)
        acc[m][i] = __builtin_amdgcn_mfma_f32_16x16x32_bf16(a, wf[i], acc[m][i], 0, 0, 0);
    }
  }

  #pragma unroll
  for (int m = 0; m < 2; ++m)
    #pragma unroll
    for (int i = 0; i < 8; ++i) {
      const int ct = wave*8 + i;
      uint2 q;
      q.x = (uint)f2b(acc[m][i][0]) | ((uint)f2b(acc[m][i][1]) << 16);
      q.y = (uint)f2b(acc[m][i][2]) | ((uint)f2b(acc[m][i][3]) << 16);
      *reinterpret_cast<uint2*>(gxF + ((size_t)((tloc*64 + ct)*4 + (mt0+m))*64 + lane)*4) = q;
    }
}

// --------------------------- fused recurrent scan --------------------------
// Blocks [0, 4*nL1): layer1 chunk t0_l1. Rest: layer0 chunk t0_l0.
// 256 thr, 4 waves, 1 wave/SIMD. Wave w owns units [64w,64w+64) x 4 gates =
// 16 tiles t=g*4+j (gate g, cols g*256 + w*64 + j*16).
// Weights/wave: kc0..3 AGPR-pinned (64 frags), kc4..5 arch VGPR (32),
// kc6..7 LDS (32). 4 passes/step (gate i,f,g,o), acc[4] per pass.
__global__ __launch_bounds__(256)
__attribute__((amdgpu_waves_per_eu(1, 1)))
void lstm_scan_fused(
    const ushort* __restrict__ gxF0, const ushort* __restrict__ gxF1,
    const ushort* __restrict__ Whh0, const ushort* __restrict__ Whh1,
    ushort* __restrict__ hs_out,     // L0: chunk buffer [CH][64][256] bf16
    float* __restrict__ hsum_out,    // L1: [64][256]
    ushort* __restrict__ hst0, ushort* __restrict__ hst1,
    float* __restrict__ cst0, float* __restrict__ cst1,
    float* __restrict__ hacc_state,  // L1: [4][256][16]
    int t0_l0, int t0_l1, int nL1)
{
  __shared__ __align__(16) char sW[131072];   // [4 waves][32 frags][1024B]
  __shared__ __align__(16) char sH[8192];     // h (single buffer, swizzled)

  const int tid = threadIdx.x;
  const int wave = tid >> 6, lane = tid & 63;
  const int l15 = lane & 15, lhi = lane >> 4;
  const int isL0 = (blockIdx.x >= (uint)(4*nL1));
  const int grp  = blockIdx.x - (isL0 ? 4*nL1 : 0);

  const ushort* gxF     = isL0 ? gxF0 : gxF1;
  const ushort* Whh     = isL0 ? Whh0 : Whh1;
  ushort*       h_state = isL0 ? hst0 : hst1;
  float*        c_state = isL0 ? cst0 : cst1;
  const int     t0      = isL0 ? t0_l0 : t0_l1;

  // ---- load weights (once): AGPR 64 / arch 32 / LDS 32 frags per wave ----
  bf16x8 wa[16][4];                            // kc 0..3 -> AGPR (pinned)
  bf16x8 wv[16][2];                            // kc 4..5 -> arch VGPR
  #pragma unroll
  for (int t = 0; t < 16; ++t) {
    const int g = t >> 2, j = t & 3;
    const ushort* wp = Whh + (size_t)(g*256 + wave*64 + j*16 + l15) * HID;
    #pragma unroll
    for (int kc = 0; kc < 4; ++kc)
      wa[t][kc] = *reinterpret_cast<const bf16x8*>(wp + kc*32 + lhi*8);
    #pragma unroll
    for (int kc = 4; kc < 6; ++kc)
      wv[t][kc-4] = *reinterpret_cast<const bf16x8*>(wp + kc*32 + lhi*8);
    #pragma unroll
    for (int kc = 6; kc < 8; ++kc) {
      bf16x8 w = *reinterpret_cast<const bf16x8*>(wp + kc*32 + lhi*8);
      *reinterpret_cast<bf16x8*>(&sW[((wave*32 + (kc-6)*16 + t) << 10) + lane*16]) = w;
    }
  }
  // one-time AGPR placement bias; all uses below are builtin MFMAs (av-class
  // operands on gfx950), so hazards stay compiler-managed.
  #pragma unroll
  for (int t = 0; t < 16; ++t)
    #pragma unroll
    for (int kc = 0; kc < 4; ++kc)
      asm("" : "+a"(wa[t][kc]));

  // ---- init / restore h in LDS ----
  if (t0 == 0) {
    for (int i = tid; i < 2048; i += 256) reinterpret_cast<uint*>(sH)[i] = 0u;
  } else {
    const uint* src = reinterpret_cast<const uint*>(h_state) + grp*2048;
    for (int i = tid; i < 2048; i += 256) reinterpret_cast<uint*>(sH)[i] = src[i];
  }

  float c[16], hacc[16], ii[16];
  if (t0 == 0) {
    #pragma unroll
    for (int i = 0; i < 16; ++i) { c[i] = 0.f; hacc[i] = 0.f; }
  } else {
    const float* cs = c_state + ((size_t)grp*256 + tid)*16;
    #pragma unroll
    for (int i = 0; i < 16; ++i) c[i] = cs[i];
    if (!isL0) {
      const float* ha = hacc_state + ((size_t)grp*256 + tid)*16;
      #pragma unroll
      for (int i = 0; i < 16; ++i) hacc[i] = ha[i];
    } else {
      #pragma unroll
      for (int i = 0; i < 16; ++i) hacc[i] = 0.f;
    }
  }

  // gx uint2 for (flat = tloc*4 + gate, j): ct = (flat&3)*16 + wave*4 + j
  #define GX_LD(flat, j) (*reinterpret_cast<const uint2*>( \
      gxF + ((size_t)((((flat) >> 2)*64 + ((flat)&3)*16 + wave*4 + (j))*4 + grp)*64 + lane)*4))
  // A-fragment (old h) read, swizzle matches writer
  #define LD_A(kc) (*reinterpret_cast<const bf16x8*>(&sH[ \
      (uint)(l15*512 + ((kc)*32 + lhi*8)*2) ^ ((uint)(l15 & 7) << 4)]))
  // weight fragment (t, kc): AGPR / arch / LDS, folded at compile time
  #define LD_W(t, kc) ((kc) < 4 ? wa[t][kc] : (kc) < 6 ? wv[t][(kc)-4] : \
      *reinterpret_cast<const bf16x8*>(&sW[((wave*32 + ((kc)-6)*16 + (t)) << 10) + lane*16]))
  // one pass: gate p, tiles p*4..p*4+3; consume qb, refill qb for flat+2
  #define DO_PASS(p, qb, flat) \
    { \
      _Pragma("unroll") \
      for (int j = 0; j < 4; ++j) { \
        uint2 q = qb[j]; \
        acc[j][0] = b2f(q.x & 0xffffu); acc[j][1] = b2f(q.x >> 16); \
        acc[j][2] = b2f(q.y & 0xffffu); acc[j][3] = b2f(q.y >> 16); \
      } \
      { const int fn = ((flat) + 2) & (CH*4 - 1); \
        _Pragma("unroll") \
        for (int j = 0; j < 4; ++j) qb[j] = GX_LD(fn, j); } \
      _Pragma("unroll") \
      for (int kc = 0; kc < 8; ++kc) { \
        bf16x8 a = LD_A(kc); \
        _Pragma("unroll") \
        for (int j = 0; j < 4; ++j) \
          acc[j] = __builtin_amdgcn_mfma_f32_16x16x32_bf16(a, LD_W((p)*4 + j, kc), acc[j], 0, 0, 0); \
      } \
    }

  // ---- prefetch gx for flats 0,1 ----
  uint2 q0[4], q1[4];
  #pragma unroll
  for (int j = 0; j < 4; ++j) { q0[j] = GX_LD(0, j); q1[j] = GX_LD(1, j); }

  __syncthreads();

  #pragma unroll 1
  for (int tloc = 0; tloc < CH; ++tloc) {
    const int fb = tloc*4;
    f32x4 acc[4];

    DO_PASS(0, q0, fb + 0)                     // gate i
    #pragma unroll
    for (int j = 0; j < 4; ++j)
      #pragma unroll
      for (int r = 0; r < 4; ++r) ii[j*4 + r] = sigm(acc[j][r]);

    DO_PASS(1, q1, fb + 1)                     // gate f
    #pragma unroll
    for (int j = 0; j < 4; ++j)
      #pragma unroll
      for (int r = 0; r < 4; ++r) c[j*4 + r] *= sigm(acc[j][r]);

    DO_PASS(2, q0, fb + 2)                     // gate g
    #pragma unroll
    for (int j = 0; j < 4; ++j)
      #pragma unroll
      for (int r = 0; r < 4; ++r)
        c[j*4 + r] = __builtin_fmaf(ii[j*4 + r], tanhf_fast(acc[j][r]), c[j*4 + r]);

    DO_PASS(3, q1, fb + 3)                     // gate o
    __syncthreads();             // all reads of old h complete
    #pragma unroll
    for (int j = 0; j < 4; ++j)
      #pragma unroll
      for (int r = 0; r < 4; ++r) {
        const int idx = j*4 + r;
        float h = sigm(acc[j][r]) * tanhf_fast(c[idx]);
        if (!isL0) hacc[idx] += h;
        const int b = lhi*4 + r;
        const int u = wave*64 + j*16 + l15;
        const uint wb = (uint)(b*512 + u*2) ^ ((uint)(b & 7) << 4);
        *reinterpret_cast<ushort*>(&sH[wb]) = f2b(h);
        if (isL0)
          hs_out[((size_t)tloc*64 + grp*16 + b)*256 + u] = f2b(h);
      }
    __syncthreads();             // new h fully written
  }

  // ---- save state ----
  {
    uint* dst = reinterpret_cast<uint*>(h_state) + grp*2048;
    const uint* src = reinterpret_cast<const uint*>(sH);
    for (int i = tid; i < 2048; i += 256) dst[i] = src[i];
    float* cs = c_state + ((size_t)grp*256 + tid)*16;
    #pragma unroll
    for (int i = 0; i < 16; ++i) cs[i] = c[i];
    if (!isL0) {
      float* ha = hacc_state + ((size_t)grp*256 + tid)*16;
      #pragma unroll
      for (int i = 0; i < 16; ++i) ha[i] = hacc[i];
      #pragma unroll
      for (int j = 0; j < 4; ++j)
        #pragma unroll
        for (int r = 0; r < 4; ++r) {
          const int b = lhi*4 + r;
          const int u = wave*64 + j*16 + l15;
          hsum_out[((size_t)grp*16 + b)*256 + u] = hacc[j*4 + r];
        }
    }
  }
  #undef GX_LD
  #undef LD_A
  #undef LD_W
  #undef DO_PASS
}

// ------------------------------- final fc ---------------------------------
__global__ void fc_kernel(const float* __restrict__ hsum, const float* __restrict__ Wfc,
                          const float* __restrict__ bfc, float* __restrict__ out)
{
  int tid = threadIdx.x;
  if (tid < 640) {
    int b = tid / 10, o = tid - b*10;
    const float* hp = hsum + b*256;
    const float* wp = Wfc + o*256;
    float s = 0.f;
    #pragma unroll 8
    for (int u = 0; u < 256; ++u) s = __builtin_fmaf(hp[u], wp[u], s);
    out[tid] = s * (1.f/1024.f) + bfc[o];
  }
}

extern "C" void kernel_launch(void* const* d_in, const int* in_sizes, int n_in,
                              void* d_out, int out_size, void* d_ws, size_t ws_size,
                              hipStream_t stream)
{
  const float* x    = (const float*)d_in[0];
  const float* Wih0 = (const float*)d_in[1];
  const float* Whh0 = (const float*)d_in[2];
  const float* bih0 = (const float*)d_in[3];
  const float* bhh0 = (const float*)d_in[4];
  const float* Wih1 = (const float*)d_in[5];
  const float* Whh1 = (const float*)d_in[6];
  const float* bih1 = (const float*)d_in[7];
  const float* bhh1 = (const float*)d_in[8];
  const float* Wfc  = (const float*)d_in[9];
  const float* bfc  = (const float*)d_in[10];
  float* out = (float*)d_out;
  char* ws = (char*)d_ws;

  // ws layout (total ~42.4 MB)
  ushort* Wb    = (ushort*)(ws);                               // 1,703,936 B
  float*  bsum  = (float*)(ws + 1703936);                      // 8 KB
  ushort* gxF0  = (ushort*)(ws + 2097152);                     // 16 MB
  ushort* gxF1  = (ushort*)(ws + 2097152 + 16777216);          // 16 MB
  ushort* hs0cA = (ushort*)(ws + 2097152 + 2*16777216);        // 4 MB
  ushort* hs0cB = (ushort*)(ws + 2097152 + 2*16777216 + 4194304);
  char*   st    = ws + 2097152 + 2*16777216 + 2*4194304;
  float*  hsum  = (float*)(st);                                // 64 KB
  ushort* hst0  = (ushort*)(st + 65536);                       // 32 KB
  ushort* hst1  = (ushort*)(st + 98304);                       // 32 KB
  float*  cst0  = (float*)(st + 131072);                       // 64 KB
  float*  cst1  = (float*)(st + 196608);                       // 64 KB
  float*  hast  = (float*)(st + 262144);                       // 64 KB

  hipLaunchKernelGGL(convert_weights, dim3(3328), dim3(256), 0, stream,
                     Wih0, Whh0, Wih1, Whh1, bih0, bhh0, bih1, bhh1, Wb, bsum);

  const ushort* Whh0b = Wb + 65536;
  const ushort* Wih1b = Wb + 327680;
  const ushort* Whh1b = Wb + 589824;

  ushort* hs0c[2] = { hs0cA, hs0cB };

  // pipeline fill: layer0 chunk 0
  hipLaunchKernelGGL((gemm_gates<0,64>), dim3(CH,2), dim3(512), 0, stream,
                     (const void*)x, Wb, bsum, gxF0, 0);
  hipLaunchKernelGGL(lstm_scan_fused, dim3(4), dim3(256), 0, stream,
                     gxF0, gxF1, Whh0b, Whh1b, hs0c[0], hsum,
                     hst0, hst1, cst0, cst1, hast, 0, 0, /*nL1=*/0);

  for (int c = 0; c < NCH; ++c) {
    hipLaunchKernelGGL((gemm_gates<1,256>), dim3(CH,2), dim3(512), 0, stream,
                       (const void*)hs0c[c & 1], Wih1b, bsum + 1024, gxF1, c*CH);
    const int nL0 = (c + 1 < NCH) ? 1 : 0;
    if (nL0)
      hipLaunchKernelGGL((gemm_gates<0,64>), dim3(CH,2), dim3(512), 0, stream,
                         (const void*)x, Wb, bsum, gxF0, (c+1)*CH);
    hipLaunchKernelGGL(lstm_scan_fused, dim3(4*(1+nL0)), dim3(256), 0, stream,
                       gxF0, gxF1, Whh0b, Whh1b, hs0c[(c+1) & 1], hsum,
                       hst0, hst1, cst0, cst1, hast, (c+1)*CH, c*CH, /*nL1=*/1);
  }
  hipLaunchKernelGGL(fc_kernel, dim3(1), dim3(640), 0, stream, hsum, Wfc, bfc, out);
}

// Round 8
// 5286.448 us; speedup vs baseline: 2.9351x; 1.4157x over previous
//
#include <hip/hip_runtime.h>
#include <stdint.h>
#include <stddef.h>

// LSTM 2-layer, B=64,T=1024,D=64,H=256 -> fc(mean_t h)  [MI355X gfx950]
// R8: scan = 4 WGs x 512 thr (8 waves, 2 waves/SIMD for cross-wave pipe
// overlap — R7's 1 wave/SIMD serialized all pipes through one issue port,
// 6.25us/step). Weights still fully CU-resident: per wave 45 frags in regs
// (180 of 256 unified) + 19 frags in LDS; 8 waves -> 360KB regs + 152KB LDS
// = 512KB. sH 8KB -> LDS 163840 (the 160KB cap exactly). Working set ~70
// regs via 1-gate passes. amdgpu_waves_per_eu(2,2) -> 256-reg budget (the
// attribute that actually worked in R7; launch_bounds alone gave 128).
// All-builtin MFMAs. Fused launch: scan0(c+1) || scan1(c).

#define T_LEN 1024
#define NB    64
#define DIN   64
#define HID   256
#define G4    1024
#define CH    128
#define NCH   (T_LEN/CH)

typedef __attribute__((ext_vector_type(8))) short  bf16x8;
typedef __attribute__((ext_vector_type(4))) float  f32x4;

__device__ __forceinline__ ushort f2b(float x) {      // fp32 -> bf16 RNE
  uint u = __float_as_uint(x);
  uint r = (u + 0x7fffu + ((u >> 16) & 1u)) >> 16;
  return (ushort)r;
}
__device__ __forceinline__ float b2f(uint u16) {      // bf16 -> fp32 exact
  return __uint_as_float(u16 << 16);
}
__device__ __forceinline__ float sigm(float x) {
  float e = __expf(-x);
  return __builtin_amdgcn_rcpf(1.f + e);
}
__device__ __forceinline__ float tanhf_fast(float x) {
  x = fmaxf(-20.f, fminf(20.f, x));                   // exact for tanh, NaN-proof
  float e = __expf(-2.f * x);
  return (1.f - e) * __builtin_amdgcn_rcpf(1.f + e);
}

// ---------------- weight convert (fp32->bf16) + bias sums -----------------
__global__ void convert_weights(const float* __restrict__ Wih0, const float* __restrict__ Whh0,
                                const float* __restrict__ Wih1, const float* __restrict__ Whh1,
                                const float* __restrict__ bih0, const float* __restrict__ bhh0,
                                const float* __restrict__ bih1, const float* __restrict__ bhh1,
                                ushort* __restrict__ Wb, float* __restrict__ bsum)
{
  int i = blockIdx.x * 256 + threadIdx.x;
  const int n0 = G4*DIN, n1 = G4*HID;
  const int total = n0 + 3*n1;                 // 851968
  if (i < total) {
    float v;
    if (i < n0)           v = Wih0[i];
    else if (i < n0+n1)   v = Whh0[i-n0];
    else if (i < n0+2*n1) v = Wih1[i-n0-n1];
    else                  v = Whh1[i-n0-2*n1];
    Wb[i] = f2b(v);
  }
  if (i < G4)        bsum[i] = bih0[i] + bhh0[i];
  else if (i < 2*G4) bsum[i] = bih1[i-G4] + bhh1[i-G4];
}

// ------------- input-projection GEMM: gx[t] = A_t @ W^T + bias -------------
// SRC=0: A = x fp32 [B][T][DIN]  (KDIM=64)
// SRC=1: A = hs0 chunk bf16 [CH][64][HID] (KDIM=256)
// grid (CH, 2): blockIdx.y picks 2 of the 4 m-tiles.
// Output gxF bf16 in MFMA-fragment order: [tloc][ct 0..63][grp 0..3][lane][r]
template<int SRC, int KDIM>
__global__ __launch_bounds__(512) void gemm_gates(
    const void* __restrict__ Asrc, const ushort* __restrict__ W,
    const float* __restrict__ bias, ushort* __restrict__ gxF, int t0)
{
  __shared__ __align__(16) char sA[64 * KDIM * 2];
  const int tid  = threadIdx.x;
  const int wave = tid >> 6, lane = tid & 63;
  const int l15 = lane & 15, lhi = lane >> 4;
  const int tloc = blockIdx.x;
  const int mt0 = blockIdx.y * 2;
  const int t = t0 + tloc;

  if (SRC == 0) {
    const float* x = (const float*)Asrc;
    int b = tid >> 3, k8 = (tid & 7) * 8;
    const float* xp = x + ((size_t)b * T_LEN + t) * DIN + k8;
    float4 v0 = *(const float4*)xp;
    float4 v1 = *(const float4*)(xp + 4);
    bf16x8 pv;
    pv[0]=(short)f2b(v0.x); pv[1]=(short)f2b(v0.y); pv[2]=(short)f2b(v0.z); pv[3]=(short)f2b(v0.w);
    pv[4]=(short)f2b(v1.x); pv[5]=(short)f2b(v1.y); pv[6]=(short)f2b(v1.z); pv[7]=(short)f2b(v1.w);
    uint bo = (uint)(b * KDIM * 2 + k8 * 2) ^ ((uint)(b & 7) << 4);
    *reinterpret_cast<bf16x8*>(&sA[bo]) = pv;
  } else {
    const ushort* hs = (const ushort*)Asrc;
    int b = tid >> 3, kb = tid & 7;
    #pragma unroll
    for (int j = 0; j < KDIM/64; ++j) {
      int k8 = (kb + j*8) * 8;
      bf16x8 v = *reinterpret_cast<const bf16x8*>(hs + ((size_t)tloc * 64 + b) * KDIM + k8);
      uint bo = (uint)(b * KDIM * 2 + k8 * 2) ^ ((uint)(b & 7) << 4);
      *reinterpret_cast<bf16x8*>(&sA[bo]) = v;
    }
  }
  __syncthreads();

  float bb[8];
  #pragma unroll
  for (int i = 0; i < 8; ++i) bb[i] = bias[(wave*8 + i)*16 + l15];

  f32x4 acc[2][8];
  #pragma unroll
  for (int m = 0; m < 2; ++m)
    #pragma unroll
    for (int i = 0; i < 8; ++i) {
      acc[m][i][0] = bb[i]; acc[m][i][1] = bb[i];
      acc[m][i][2] = bb[i]; acc[m][i][3] = bb[i];
    }

  #pragma unroll
  for (int kc = 0; kc < KDIM/32; ++kc) {
    const int koff = kc*32 + lhi*8;
    bf16x8 wf[8];
    #pragma unroll
    for (int i = 0; i < 8; ++i)
      wf[i] = *reinterpret_cast<const bf16x8*>(W + (size_t)((wave*8 + i)*16 + l15) * KDIM + koff);
    #pragma unroll
    for (int m = 0; m < 2; ++m) {
      const int row = (mt0 + m)*16 + l15;
      const uint bo = (uint)(row * KDIM * 2 + koff * 2) ^ ((uint)(row & 7) << 4);
      bf16x8 a = *reinterpret_cast<const bf16x8*>(&sA[bo]);
      #pragma unroll
      for (int i = 0; i < 8; ++i)
        acc[m][i] = __builtin_amdgcn_mfma_f32_16x16x32_bf16(a, wf[i], acc[m][i], 0, 0, 0);
    }
  }

  #pragma unroll
  for (int m = 0; m < 2; ++m)
    #pragma unroll
    for (int i = 0; i < 8; ++i) {
      const int ct = wave*8 + i;
      uint2 q;
      q.x = (uint)f2b(acc[m][i][0]) | ((uint)f2b(acc[m][i][1]) << 16);
      q.y = (uint)f2b(acc[m][i][2]) | ((uint)f2b(acc[m][i][3]) << 16);
      *reinterpret_cast<uint2*>(gxF + ((size_t)((tloc*64 + ct)*4 + (mt0+m))*64 + lane)*4) = q;
    }
}

// --------------------------- fused recurrent scan --------------------------
// Blocks [0, 4*nL1): layer1 chunk t0_l1. Rest: layer0 chunk t0_l0.
// 512 thr, 8 waves, 2 waves/SIMD. Wave w owns units [32w,32w+32) x 4 gates =
// 8 tiles t=g*2+j (gate g, cols g*256 + w*32 + j*16).
// Frags/wave: 45 in regs (kc0..4 all t; kc5 t0..4), 19 in LDS (kc5 t5..7,
// kc6..7 all t). 4 passes/step (one gate each), acc[2]/pass, thread owns
// 8 h-elems (j 0..1, r 0..3). h single-buffer LDS 8KB XOR-swizzled.
__global__ __launch_bounds__(512)
__attribute__((amdgpu_waves_per_eu(2, 2)))
void lstm_scan_fused(
    const ushort* __restrict__ gxF0, const ushort* __restrict__ gxF1,
    const ushort* __restrict__ Whh0, const ushort* __restrict__ Whh1,
    ushort* __restrict__ hs_out,     // L0: chunk buffer [CH][64][256] bf16
    float* __restrict__ hsum_out,    // L1: [64][256]
    ushort* __restrict__ hst0, ushort* __restrict__ hst1,
    float* __restrict__ cst0, float* __restrict__ cst1,
    float* __restrict__ hacc_state,  // L1: [4][512][8]
    int t0_l0, int t0_l1, int nL1)
{
  __shared__ __align__(16) char sW[155648];   // [8 waves][19 frags][1024B]
  __shared__ __align__(16) char sH[8192];     // h (single buffer, swizzled)

  const int tid = threadIdx.x;
  const int wave = tid >> 6, lane = tid & 63;
  const int l15 = lane & 15, lhi = lane >> 4;
  const int isL0 = (blockIdx.x >= (uint)(4*nL1));
  const int grp  = blockIdx.x - (isL0 ? 4*nL1 : 0);

  const ushort* gxF     = isL0 ? gxF0 : gxF1;
  const ushort* Whh     = isL0 ? Whh0 : Whh1;
  ushort*       h_state = isL0 ? hst0 : hst1;
  float*        c_state = isL0 ? cst0 : cst1;
  const int     t0      = isL0 ? t0_l0 : t0_l1;

  // ---- load weights (once): 45 frags regs + 19 frags LDS per wave ----
  bf16x8 wv[8][6];                             // sparse: 45 live entries
  #pragma unroll
  for (int t = 0; t < 8; ++t) {
    const int g = t >> 1, j = t & 1;
    const ushort* wp = Whh + (size_t)(g*256 + wave*32 + j*16 + l15) * HID;
    #pragma unroll
    for (int kc = 0; kc < 8; ++kc) {
      bf16x8 w = *reinterpret_cast<const bf16x8*>(wp + kc*32 + lhi*8);
      if (kc >= 6 || (kc == 5 && t >= 5)) {
        const int fid = (kc == 6) ? t : (kc == 7) ? (8 + t) : (16 + (t - 5));
        *reinterpret_cast<bf16x8*>(&sW[((wave*19 + fid) << 10) + lane*16]) = w;
      } else {
        wv[t][kc] = w;
      }
    }
  }

  // ---- init / restore h in LDS ----
  if (t0 == 0) {
    for (int i = tid; i < 2048; i += 512) reinterpret_cast<uint*>(sH)[i] = 0u;
  } else {
    const uint* src = reinterpret_cast<const uint*>(h_state) + grp*2048;
    for (int i = tid; i < 2048; i += 512) reinterpret_cast<uint*>(sH)[i] = src[i];
  }

  float c[8], hacc[8], ii[8];
  if (t0 == 0) {
    #pragma unroll
    for (int i = 0; i < 8; ++i) { c[i] = 0.f; hacc[i] = 0.f; }
  } else {
    const float* cs = c_state + ((size_t)grp*512 + tid)*8;
    #pragma unroll
    for (int i = 0; i < 8; ++i) c[i] = cs[i];
    if (!isL0) {
      const float* ha = hacc_state + ((size_t)grp*512 + tid)*8;
      #pragma unroll
      for (int i = 0; i < 8; ++i) hacc[i] = ha[i];
    } else {
      #pragma unroll
      for (int i = 0; i < 8; ++i) hacc[i] = 0.f;
    }
  }

  // gx uint2 for (flat = tloc*4 + gate, j): ct = (flat&3)*16 + wave*2 + j
  #define GX_LD(flat, j) (*reinterpret_cast<const uint2*>( \
      gxF + ((size_t)((((flat) >> 2)*64 + ((flat)&3)*16 + wave*2 + (j))*4 + grp)*64 + lane)*4))
  // A-fragment (old h) read, swizzle matches writer
  #define LD_A(kc) (*reinterpret_cast<const bf16x8*>(&sH[ \
      (uint)(l15*512 + ((kc)*32 + lhi*8)*2) ^ ((uint)(l15 & 7) << 4)]))
  // weight fragment (t, kc): regs or LDS, folded at compile time
  #define LD_W(t, kc) (((kc) >= 6 || ((kc) == 5 && (t) >= 5)) ? \
      *reinterpret_cast<const bf16x8*>(&sW[((wave*19 + \
        ((kc) == 6 ? (t) : (kc) == 7 ? (8 + (t)) : (16 + (t) - 5))) << 10) + lane*16]) \
      : wv[t][kc])
  // one pass: gate p, tiles p*2, p*2+1; consume qb, refill qb for flat+2
  #define DO_PASS(p, qb, flat) \
    { \
      _Pragma("unroll") \
      for (int j = 0; j < 2; ++j) { \
        uint2 q = qb[j]; \
        acc[j][0] = b2f(q.x & 0xffffu); acc[j][1] = b2f(q.x >> 16); \
        acc[j][2] = b2f(q.y & 0xffffu); acc[j][3] = b2f(q.y >> 16); \
      } \
      { const int fn = ((flat) + 2) & (CH*4 - 1); \
        _Pragma("unroll") \
        for (int j = 0; j < 2; ++j) qb[j] = GX_LD(fn, j); } \
      _Pragma("unroll") \
      for (int kc = 0; kc < 8; ++kc) { \
        bf16x8 a = LD_A(kc); \
        _Pragma("unroll") \
        for (int j = 0; j < 2; ++j) \
          acc[j] = __builtin_amdgcn_mfma_f32_16x16x32_bf16(a, LD_W((p)*2 + j, kc), acc[j], 0, 0, 0); \
      } \
    }

  // ---- prefetch gx for flats 0,1 ----
  uint2 q0[2], q1[2];
  #pragma unroll
  for (int j = 0; j < 2; ++j) { q0[j] = GX_LD(0, j); q1[j] = GX_LD(1, j); }

  __syncthreads();

  #pragma unroll 1
  for (int tloc = 0; tloc < CH; ++tloc) {
    const int fb = tloc*4;
    f32x4 acc[2];

    DO_PASS(0, q0, fb + 0)                     // gate i
    #pragma unroll
    for (int j = 0; j < 2; ++j)
      #pragma unroll
      for (int r = 0; r < 4; ++r) ii[j*4 + r] = sigm(acc[j][r]);

    DO_PASS(1, q1, fb + 1)                     // gate f
    #pragma unroll
    for (int j = 0; j < 2; ++j)
      #pragma unroll
      for (int r = 0; r < 4; ++r) c[j*4 + r] *= sigm(acc[j][r]);

    DO_PASS(2, q0, fb + 2)                     // gate g
    #pragma unroll
    for (int j = 0; j < 2; ++j)
      #pragma unroll
      for (int r = 0; r < 4; ++r)
        c[j*4 + r] = __builtin_fmaf(ii[j*4 + r], tanhf_fast(acc[j][r]), c[j*4 + r]);

    DO_PASS(3, q1, fb + 3)                     // gate o
    __syncthreads();             // all reads of old h complete
    #pragma unroll
    for (int j = 0; j < 2; ++j)
      #pragma unroll
      for (int r = 0; r < 4; ++r) {
        const int idx = j*4 + r;
        float h = sigm(acc[j][r]) * tanhf_fast(c[idx]);
        if (!isL0) hacc[idx] += h;
        const int b = lhi*4 + r;
        const int u = wave*32 + j*16 + l15;
        const uint wb = (uint)(b*512 + u*2) ^ ((uint)(b & 7) << 4);
        *reinterpret_cast<ushort*>(&sH[wb]) = f2b(h);
        if (isL0)
          hs_out[((size_t)tloc*64 + grp*16 + b)*256 + u] = f2b(h);
      }
    __syncthreads();             // new h fully written
  }

  // ---- save state ----
  {
    uint* dst = reinterpret_cast<uint*>(h_state) + grp*2048;
    const uint* src = reinterpret_cast<const uint*>(sH);
    for (int i = tid; i < 2048; i += 512) dst[i] = src[i];
    float* cs = c_state + ((size_t)grp*512 + tid)*8;
    #pragma unroll
    for (int i = 0; i < 8; ++i) cs[i] = c[i];
    if (!isL0) {
      float* ha = hacc_state + ((size_t)grp*512 + tid)*8;
      #pragma unroll
      for (int i = 0; i < 8; ++i) ha[i] = hacc[i];
      #pragma unroll
      for (int j = 0; j < 2; ++j)
        #pragma unroll
        for (int r = 0; r < 4; ++r) {
          const int b = lhi*4 + r;
          const int u = wave*32 + j*16 + l15;
          hsum_out[((size_t)grp*16 + b)*256 + u] = hacc[j*4 + r];
        }
    }
  }
  #undef GX_LD
  #undef LD_A
  #undef LD_W
  #undef DO_PASS
}

// ------------------------------- final fc ---------------------------------
__global__ void fc_kernel(const float* __restrict__ hsum, const float* __restrict__ Wfc,
                          const float* __restrict__ bfc, float* __restrict__ out)
{
  int tid = threadIdx.x;
  if (tid < 640) {
    int b = tid / 10, o = tid - b*10;
    const float* hp = hsum + b*256;
    const float* wp = Wfc + o*256;
    float s = 0.f;
    #pragma unroll 8
    for (int u = 0; u < 256; ++u) s = __builtin_fmaf(hp[u], wp[u], s);
    out[tid] = s * (1.f/1024.f) + bfc[o];
  }
}

extern "C" void kernel_launch(void* const* d_in, const int* in_sizes, int n_in,
                              void* d_out, int out_size, void* d_ws, size_t ws_size,
                              hipStream_t stream)
{
  const float* x    = (const float*)d_in[0];
  const float* Wih0 = (const float*)d_in[1];
  const float* Whh0 = (const float*)d_in[2];
  const float* bih0 = (const float*)d_in[3];
  const float* bhh0 = (const float*)d_in[4];
  const float* Wih1 = (const float*)d_in[5];
  const float* Whh1 = (const float*)d_in[6];
  const float* bih1 = (const float*)d_in[7];
  const float* bhh1 = (const float*)d_in[8];
  const float* Wfc  = (const float*)d_in[9];
  const float* bfc  = (const float*)d_in[10];
  float* out = (float*)d_out;
  char* ws = (char*)d_ws;

  // ws layout (total ~42.4 MB)
  ushort* Wb    = (ushort*)(ws);                               // 1,703,936 B
  float*  bsum  = (float*)(ws + 1703936);                      // 8 KB
  ushort* gxF0  = (ushort*)(ws + 2097152);                     // 16 MB
  ushort* gxF1  = (ushort*)(ws + 2097152 + 16777216);          // 16 MB
  ushort* hs0cA = (ushort*)(ws + 2097152 + 2*16777216);        // 4 MB
  ushort* hs0cB = (ushort*)(ws + 2097152 + 2*16777216 + 4194304);
  char*   st    = ws + 2097152 + 2*16777216 + 2*4194304;
  float*  hsum  = (float*)(st);                                // 64 KB
  ushort* hst0  = (ushort*)(st + 65536);                       // 32 KB
  ushort* hst1  = (ushort*)(st + 98304);                       // 32 KB
  float*  cst0  = (float*)(st + 131072);                       // 64 KB
  float*  cst1  = (float*)(st + 196608);                       // 64 KB
  float*  hast  = (float*)(st + 262144);                       // 64 KB

  hipLaunchKernelGGL(convert_weights, dim3(3328), dim3(256), 0, stream,
                     Wih0, Whh0, Wih1, Whh1, bih0, bhh0, bih1, bhh1, Wb, bsum);

  const ushort* Whh0b = Wb + 65536;
  const ushort* Wih1b = Wb + 327680;
  const ushort* Whh1b = Wb + 589824;

  ushort* hs0c[2] = { hs0cA, hs0cB };

  // pipeline fill: layer0 chunk 0
  hipLaunchKernelGGL((gemm_gates<0,64>), dim3(CH,2), dim3(512), 0, stream,
                     (const void*)x, Wb, bsum, gxF0, 0);
  hipLaunchKernelGGL(lstm_scan_fused, dim3(4), dim3(512), 0, stream,
                     gxF0, gxF1, Whh0b, Whh1b, hs0c[0], hsum,
                     hst0, hst1, cst0, cst1, hast, 0, 0, /*nL1=*/0);

  for (int c = 0; c < NCH; ++c) {
    hipLaunchKernelGGL((gemm_gates<1,256>), dim3(CH,2), dim3(512), 0, stream,
                       (const void*)hs0c[c & 1], Wih1b, bsum + 1024, gxF1, c*CH);
    const int nL0 = (c + 1 < NCH) ? 1 : 0;
    if (nL0)
      hipLaunchKernelGGL((gemm_gates<0,64>), dim3(CH,2), dim3(512), 0, stream,
                         (const void*)x, Wb, bsum, gxF0, (c+1)*CH);
    hipLaunchKernelGGL(lstm_scan_fused, dim3(4*(1+nL0)), dim3(512), 0, stream,
                       gxF0, gxF1, Whh0b, Whh1b, hs0c[(c+1) & 1], hsum,
                       hst0, hst1, cst0, cst1, hast, (c+1)*CH, c*CH, /*nL1=*/1);
  }
  hipLaunchKernelGGL(fc_kernel, dim3(1), dim3(640), 0, stream, hsum, Wfc, bfc, out);
}

// Round 9
// 4165.466 us; speedup vs baseline: 3.7250x; 1.2691x over previous
//
#include <hip/hip_runtime.h>
#include <stdint.h>
#include <stddef.h>

// LSTM 2-layer, B=64,T=1024,D=64,H=256 -> fc(mean_t h)  [MI355X gfx950]
// R9: kc-major scan step — read each h A-fragment ONCE per step (8 ds_reads,
// was 32 across 4 gate-passes), all-gate acc[8] live, one 64-MFMA block.
// sH double-buffered (2x8KB) -> 1 barrier/step (was 2). sW 144KB (18 frags/
// wave LDS), 46 frags/wave in regs (arch128+acc128 unified split, proven R8).
// 512 thr, 8 waves, 2 waves/SIMD, amdgpu_waves_per_eu(2,2).
// Fused launch: scan0(c+1) || scan1(c).

#define T_LEN 1024
#define NB    64
#define DIN   64
#define HID   256
#define G4    1024
#define CH    128
#define NCH   (T_LEN/CH)

typedef __attribute__((ext_vector_type(8))) short  bf16x8;
typedef __attribute__((ext_vector_type(4))) float  f32x4;

__device__ __forceinline__ ushort f2b(float x) {      // fp32 -> bf16 RNE
  uint u = __float_as_uint(x);
  uint r = (u + 0x7fffu + ((u >> 16) & 1u)) >> 16;
  return (ushort)r;
}
__device__ __forceinline__ float b2f(uint u16) {      // bf16 -> fp32 exact
  return __uint_as_float(u16 << 16);
}
__device__ __forceinline__ float sigm(float x) {
  float e = __expf(-x);
  return __builtin_amdgcn_rcpf(1.f + e);
}
__device__ __forceinline__ float tanhf_fast(float x) {
  x = fmaxf(-20.f, fminf(20.f, x));                   // exact for tanh, NaN-proof
  float e = __expf(-2.f * x);
  return (1.f - e) * __builtin_amdgcn_rcpf(1.f + e);
}

// ---------------- weight convert (fp32->bf16) + bias sums -----------------
__global__ void convert_weights(const float* __restrict__ Wih0, const float* __restrict__ Whh0,
                                const float* __restrict__ Wih1, const float* __restrict__ Whh1,
                                const float* __restrict__ bih0, const float* __restrict__ bhh0,
                                const float* __restrict__ bih1, const float* __restrict__ bhh1,
                                ushort* __restrict__ Wb, float* __restrict__ bsum)
{
  int i = blockIdx.x * 256 + threadIdx.x;
  const int n0 = G4*DIN, n1 = G4*HID;
  const int total = n0 + 3*n1;                 // 851968
  if (i < total) {
    float v;
    if (i < n0)           v = Wih0[i];
    else if (i < n0+n1)   v = Whh0[i-n0];
    else if (i < n0+2*n1) v = Wih1[i-n0-n1];
    else                  v = Whh1[i-n0-2*n1];
    Wb[i] = f2b(v);
  }
  if (i < G4)        bsum[i] = bih0[i] + bhh0[i];
  else if (i < 2*G4) bsum[i] = bih1[i-G4] + bhh1[i-G4];
}

// ------------- input-projection GEMM: gx[t] = A_t @ W^T + bias -------------
// SRC=0: A = x fp32 [B][T][DIN]  (KDIM=64)
// SRC=1: A = hs0 chunk bf16 [CH][64][HID] (KDIM=256)
// grid (CH, 2): blockIdx.y picks 2 of the 4 m-tiles.
// Output gxF bf16 in MFMA-fragment order: [tloc][ct 0..63][grp 0..3][lane][r]
template<int SRC, int KDIM>
__global__ __launch_bounds__(512) void gemm_gates(
    const void* __restrict__ Asrc, const ushort* __restrict__ W,
    const float* __restrict__ bias, ushort* __restrict__ gxF, int t0)
{
  __shared__ __align__(16) char sA[64 * KDIM * 2];
  const int tid  = threadIdx.x;
  const int wave = tid >> 6, lane = tid & 63;
  const int l15 = lane & 15, lhi = lane >> 4;
  const int tloc = blockIdx.x;
  const int mt0 = blockIdx.y * 2;
  const int t = t0 + tloc;

  if (SRC == 0) {
    const float* x = (const float*)Asrc;
    int b = tid >> 3, k8 = (tid & 7) * 8;
    const float* xp = x + ((size_t)b * T_LEN + t) * DIN + k8;
    float4 v0 = *(const float4*)xp;
    float4 v1 = *(const float4*)(xp + 4);
    bf16x8 pv;
    pv[0]=(short)f2b(v0.x); pv[1]=(short)f2b(v0.y); pv[2]=(short)f2b(v0.z); pv[3]=(short)f2b(v0.w);
    pv[4]=(short)f2b(v1.x); pv[5]=(short)f2b(v1.y); pv[6]=(short)f2b(v1.z); pv[7]=(short)f2b(v1.w);
    uint bo = (uint)(b * KDIM * 2 + k8 * 2) ^ ((uint)(b & 7) << 4);
    *reinterpret_cast<bf16x8*>(&sA[bo]) = pv;
  } else {
    const ushort* hs = (const ushort*)Asrc;
    int b = tid >> 3, kb = tid & 7;
    #pragma unroll
    for (int j = 0; j < KDIM/64; ++j) {
      int k8 = (kb + j*8) * 8;
      bf16x8 v = *reinterpret_cast<const bf16x8*>(hs + ((size_t)tloc * 64 + b) * KDIM + k8);
      uint bo = (uint)(b * KDIM * 2 + k8 * 2) ^ ((uint)(b & 7) << 4);
      *reinterpret_cast<bf16x8*>(&sA[bo]) = v;
    }
  }
  __syncthreads();

  float bb[8];
  #pragma unroll
  for (int i = 0; i < 8; ++i) bb[i] = bias[(wave*8 + i)*16 + l15];

  f32x4 acc[2][8];
  #pragma unroll
  for (int m = 0; m < 2; ++m)
    #pragma unroll
    for (int i = 0; i < 8; ++i) {
      acc[m][i][0] = bb[i]; acc[m][i][1] = bb[i];
      acc[m][i][2] = bb[i]; acc[m][i][3] = bb[i];
    }

  #pragma unroll
  for (int kc = 0; kc < KDIM/32; ++kc) {
    const int koff = kc*32 + lhi*8;
    bf16x8 wf[8];
    #pragma unroll
    for (int i = 0; i < 8; ++i)
      wf[i] = *reinterpret_cast<const bf16x8*>(W + (size_t)((wave*8 + i)*16 + l15) * KDIM + koff);
    #pragma unroll
    for (int m = 0; m < 2; ++m) {
      const int row = (mt0 + m)*16 + l15;
      const uint bo = (uint)(row * KDIM * 2 + koff * 2) ^ ((uint)(row & 7) << 4);
      bf16x8 a = *reinterpret_cast<const bf16x8*>(&sA[bo]);
      #pragma unroll
      for (int i = 0; i < 8; ++i)
        acc[m][i] = __builtin_amdgcn_mfma_f32_16x16x32_bf16(a, wf[i], acc[m][i], 0, 0, 0);
    }
  }

  #pragma unroll
  for (int m = 0; m < 2; ++m)
    #pragma unroll
    for (int i = 0; i < 8; ++i) {
      const int ct = wave*8 + i;
      uint2 q;
      q.x = (uint)f2b(acc[m][i][0]) | ((uint)f2b(acc[m][i][1]) << 16);
      q.y = (uint)f2b(acc[m][i][2]) | ((uint)f2b(acc[m][i][3]) << 16);
      *reinterpret_cast<uint2*>(gxF + ((size_t)((tloc*64 + ct)*4 + (mt0+m))*64 + lane)*4) = q;
    }
}

// --------------------------- fused recurrent scan --------------------------
// Blocks [0, 4*nL1): layer1 chunk t0_l1. Rest: layer0 chunk t0_l0.
// 512 thr, 8 waves, 2 waves/SIMD. Wave w owns units [32w,32w+32) x 4 gates =
// 8 tiles t = gate*2 + j (cols gate*256 + w*32 + j*16).
// Frags/wave: 46 in regs (kc0..4 all t; kc5 t0..5), 18 in LDS (kc5 t6..7,
// kc6..7 all t). kc-major step: 8 A ds_reads, 64 MFMAs into acc[8], then
// activations for all 4 gates. sH double-buffered -> 1 barrier/step.
__global__ __launch_bounds__(512)
__attribute__((amdgpu_waves_per_eu(2, 2)))
void lstm_scan_fused(
    const ushort* __restrict__ gxF0, const ushort* __restrict__ gxF1,
    const ushort* __restrict__ Whh0, const ushort* __restrict__ Whh1,
    ushort* __restrict__ hs_out,     // L0: chunk buffer [CH][64][256] bf16
    float* __restrict__ hsum_out,    // L1: [64][256]
    ushort* __restrict__ hst0, ushort* __restrict__ hst1,
    float* __restrict__ cst0, float* __restrict__ cst1,
    float* __restrict__ hacc_state,  // L1: [4][512][8]
    int t0_l0, int t0_l1, int nL1)
{
  __shared__ __align__(16) char sW[147456];   // [8 waves][18 frags][1024B]
  __shared__ __align__(16) char sH[16384];    // h double buffer, swizzled

  const int tid = threadIdx.x;
  const int wave = tid >> 6, lane = tid & 63;
  const int l15 = lane & 15, lhi = lane >> 4;
  const int isL0 = (blockIdx.x >= (uint)(4*nL1));
  const int grp  = blockIdx.x - (isL0 ? 4*nL1 : 0);

  const ushort* gxF     = isL0 ? gxF0 : gxF1;
  const ushort* Whh     = isL0 ? Whh0 : Whh1;
  ushort*       h_state = isL0 ? hst0 : hst1;
  float*        c_state = isL0 ? cst0 : cst1;
  const int     t0      = isL0 ? t0_l0 : t0_l1;

  // ---- load weights (once): 46 frags regs + 18 frags LDS per wave ----
  bf16x8 wv[8][6];                             // sparse: 46 live entries
  #pragma unroll
  for (int t = 0; t < 8; ++t) {
    const int g = t >> 1, j = t & 1;
    const ushort* wp = Whh + (size_t)(g*256 + wave*32 + j*16 + l15) * HID;
    #pragma unroll
    for (int kc = 0; kc < 8; ++kc) {
      bf16x8 w = *reinterpret_cast<const bf16x8*>(wp + kc*32 + lhi*8);
      if (kc >= 6 || (kc == 5 && t >= 6)) {
        const int fid = (kc == 6) ? t : (kc == 7) ? (8 + t) : (16 + (t - 6));
        *reinterpret_cast<bf16x8*>(&sW[((wave*18 + fid) << 10) + lane*16]) = w;
      } else {
        wv[t][kc] = w;
      }
    }
  }

  // ---- init / restore h into buffer 0 ----
  if (t0 == 0) {
    for (int i = tid; i < 2048; i += 512) reinterpret_cast<uint*>(sH)[i] = 0u;
  } else {
    const uint* src = reinterpret_cast<const uint*>(h_state) + grp*2048;
    for (int i = tid; i < 2048; i += 512) reinterpret_cast<uint*>(sH)[i] = src[i];
  }

  float c[8], hacc[8];
  if (t0 == 0) {
    #pragma unroll
    for (int i = 0; i < 8; ++i) { c[i] = 0.f; hacc[i] = 0.f; }
  } else {
    const float* cs = c_state + ((size_t)grp*512 + tid)*8;
    #pragma unroll
    for (int i = 0; i < 8; ++i) c[i] = cs[i];
    if (!isL0) {
      const float* ha = hacc_state + ((size_t)grp*512 + tid)*8;
      #pragma unroll
      for (int i = 0; i < 8; ++i) hacc[i] = ha[i];
    } else {
      #pragma unroll
      for (int i = 0; i < 8; ++i) hacc[i] = 0.f;
    }
  }

  // gx uint2 for tile t at step tl: ct = (t>>1)*16 + wave*2 + (t&1)
  #define GX_LD(tl, t) (*reinterpret_cast<const uint2*>( \
      gxF + ((size_t)(((tl)*64 + ((t)>>1)*16 + wave*2 + ((t)&1))*4 + grp)*64 + lane)*4))
  // A-fragment (old h) read from buffer cb, swizzle matches writer
  #define LD_A(cb, kc) (*reinterpret_cast<const bf16x8*>(&sH[(cb)*8192 + \
      ((uint)(l15*512 + ((kc)*32 + lhi*8)*2) ^ ((uint)(l15 & 7) << 4))]))
  // weight fragment (t, kc): regs or LDS, folded at compile time
  #define LD_W(t, kc) (((kc) >= 6 || ((kc) == 5 && (t) >= 6)) ? \
      *reinterpret_cast<const bf16x8*>(&sW[((wave*18 + \
        ((kc) == 6 ? (t) : (kc) == 7 ? (8 + (t)) : (16 + (t) - 6))) << 10) + lane*16]) \
      : wv[t][kc])

  // ---- prefetch gx for step 0 ----
  uint2 gxb[8];
  #pragma unroll
  for (int t = 0; t < 8; ++t) gxb[t] = GX_LD(0, t);

  __syncthreads();

  int cur = 0;
  #pragma unroll 1
  for (int tloc = 0; tloc < CH; ++tloc) {
    // 1. acc init = gx (incl. bias), all 8 tiles
    f32x4 acc[8];
    #pragma unroll
    for (int t = 0; t < 8; ++t) {
      uint2 q = gxb[t];
      acc[t][0] = b2f(q.x & 0xffffu); acc[t][1] = b2f(q.x >> 16);
      acc[t][2] = b2f(q.y & 0xffffu); acc[t][3] = b2f(q.y >> 16);
    }
    // 2. issue next step's gx loads (full step of latency cover)
    {
      const int tln = (tloc + 1) & (CH - 1);
      #pragma unroll
      for (int t = 0; t < 8; ++t) gxb[t] = GX_LD(tln, t);
    }
    // 3. kc-major MFMA block: 8 A-reads total, 64 MFMAs
    #pragma unroll
    for (int kc = 0; kc < 8; ++kc) {
      bf16x8 a = LD_A(cur, kc);
      #pragma unroll
      for (int t = 0; t < 8; ++t)
        acc[t] = __builtin_amdgcn_mfma_f32_16x16x32_bf16(a, LD_W(t, kc), acc[t], 0, 0, 0);
    }
    // 4. activations: thread owns (batch=lhi*4+r, units wave*32+j*16+l15)
    #pragma unroll
    for (int j = 0; j < 2; ++j)
      #pragma unroll
      for (int r = 0; r < 4; ++r) {
        const int idx = j*4 + r;
        float ig = sigm(acc[0 + j][r]);
        float fg = sigm(acc[2 + j][r]);
        float gg = tanhf_fast(acc[4 + j][r]);
        float og = sigm(acc[6 + j][r]);
        float cn = __builtin_fmaf(fg, c[idx], ig * gg);
        c[idx] = cn;
        float h = og * tanhf_fast(cn);
        if (!isL0) hacc[idx] += h;
        const int b = lhi*4 + r;
        const int u = wave*32 + j*16 + l15;
        const uint wb = (uint)(b*512 + u*2) ^ ((uint)(b & 7) << 4);
        *reinterpret_cast<ushort*>(&sH[(cur ^ 1)*8192 + wb]) = f2b(h);
        if (isL0)
          hs_out[((size_t)tloc*64 + grp*16 + b)*256 + u] = f2b(h);
      }
    __syncthreads();             // writes to buf cur^1 visible; reads of buf
    cur ^= 1;                    // cur were drained by each wave's lgkmcnt
  }

  // ---- save state ----
  {
    uint* dst = reinterpret_cast<uint*>(h_state) + grp*2048;
    const uint* src = reinterpret_cast<const uint*>(&sH[cur*8192]);
    for (int i = tid; i < 2048; i += 512) dst[i] = src[i];
    float* cs = c_state + ((size_t)grp*512 + tid)*8;
    #pragma unroll
    for (int i = 0; i < 8; ++i) cs[i] = c[i];
    if (!isL0) {
      float* ha = hacc_state + ((size_t)grp*512 + tid)*8;
      #pragma unroll
      for (int i = 0; i < 8; ++i) ha[i] = hacc[i];
      #pragma unroll
      for (int j = 0; j < 2; ++j)
        #pragma unroll
        for (int r = 0; r < 4; ++r) {
          const int b = lhi*4 + r;
          const int u = wave*32 + j*16 + l15;
          hsum_out[((size_t)grp*16 + b)*256 + u] = hacc[j*4 + r];
        }
    }
  }
  #undef GX_LD
  #undef LD_A
  #undef LD_W
}

// ------------------------------- final fc ---------------------------------
__global__ void fc_kernel(const float* __restrict__ hsum, const float* __restrict__ Wfc,
                          const float* __restrict__ bfc, float* __restrict__ out)
{
  int tid = threadIdx.x;
  if (tid < 640) {
    int b = tid / 10, o = tid - b*10;
    const float* hp = hsum + b*256;
    const float* wp = Wfc + o*256;
    float s = 0.f;
    #pragma unroll 8
    for (int u = 0; u < 256; ++u) s = __builtin_fmaf(hp[u], wp[u], s);
    out[tid] = s * (1.f/1024.f) + bfc[o];
  }
}

extern "C" void kernel_launch(void* const* d_in, const int* in_sizes, int n_in,
                              void* d_out, int out_size, void* d_ws, size_t ws_size,
                              hipStream_t stream)
{
  const float* x    = (const float*)d_in[0];
  const float* Wih0 = (const float*)d_in[1];
  const float* Whh0 = (const float*)d_in[2];
  const float* bih0 = (const float*)d_in[3];
  const float* bhh0 = (const float*)d_in[4];
  const float* Wih1 = (const float*)d_in[5];
  const float* Whh1 = (const float*)d_in[6];
  const float* bih1 = (const float*)d_in[7];
  const float* bhh1 = (const float*)d_in[8];
  const float* Wfc  = (const float*)d_in[9];
  const float* bfc  = (const float*)d_in[10];
  float* out = (float*)d_out;
  char* ws = (char*)d_ws;

  // ws layout (total ~42.4 MB)
  ushort* Wb    = (ushort*)(ws);                               // 1,703,936 B
  float*  bsum  = (float*)(ws + 1703936);                      // 8 KB
  ushort* gxF0  = (ushort*)(ws + 2097152);                     // 16 MB
  ushort* gxF1  = (ushort*)(ws + 2097152 + 16777216);          // 16 MB
  ushort* hs0cA = (ushort*)(ws + 2097152 + 2*16777216);        // 4 MB
  ushort* hs0cB = (ushort*)(ws + 2097152 + 2*16777216 + 4194304);
  char*   st    = ws + 2097152 + 2*16777216 + 2*4194304;
  float*  hsum  = (float*)(st);                                // 64 KB
  ushort* hst0  = (ushort*)(st + 65536);                       // 32 KB
  ushort* hst1  = (ushort*)(st + 98304);                       // 32 KB
  float*  cst0  = (float*)(st + 131072);                       // 64 KB
  float*  cst1  = (float*)(st + 196608);                       // 64 KB
  float*  hast  = (float*)(st + 262144);                       // 64 KB

  hipLaunchKernelGGL(convert_weights, dim3(3328), dim3(256), 0, stream,
                     Wih0, Whh0, Wih1, Whh1, bih0, bhh0, bih1, bhh1, Wb, bsum);

  const ushort* Whh0b = Wb + 65536;
  const ushort* Wih1b = Wb + 327680;
  const ushort* Whh1b = Wb + 589824;

  ushort* hs0c[2] = { hs0cA, hs0cB };

  // pipeline fill: layer0 chunk 0
  hipLaunchKernelGGL((gemm_gates<0,64>), dim3(CH,2), dim3(512), 0, stream,
                     (const void*)x, Wb, bsum, gxF0, 0);
  hipLaunchKernelGGL(lstm_scan_fused, dim3(4), dim3(512), 0, stream,
                     gxF0, gxF1, Whh0b, Whh1b, hs0c[0], hsum,
                     hst0, hst1, cst0, cst1, hast, 0, 0, /*nL1=*/0);

  for (int c = 0; c < NCH; ++c) {
    hipLaunchKernelGGL((gemm_gates<1,256>), dim3(CH,2), dim3(512), 0, stream,
                       (const void*)hs0c[c & 1], Wih1b, bsum + 1024, gxF1, c*CH);
    const int nL0 = (c + 1 < NCH) ? 1 : 0;
    if (nL0)
      hipLaunchKernelGGL((gemm_gates<0,64>), dim3(CH,2), dim3(512), 0, stream,
                         (const void*)x, Wb, bsum, gxF0, (c+1)*CH);
    hipLaunchKernelGGL(lstm_scan_fused, dim3(4*(1+nL0)), dim3(512), 0, stream,
                       gxF0, gxF1, Whh0b, Whh1b, hs0c[(c+1) & 1], hsum,
                       hst0, hst1, cst0, cst1, hast, (c+1)*CH, c*CH, /*nL1=*/1);
  }
  hipLaunchKernelGGL(fc_kernel, dim3(1), dim3(640), 0, stream, hsum, Wfc, bfc, out);
}

// Round 10
// 3108.593 us; speedup vs baseline: 4.9914x; 1.3400x over previous
//
#include <hip/hip_runtime.h>
#include <stdint.h>
#include <stddef.h>

// LSTM 2-layer, B=64,T=1024,D=64,H=256 -> fc(mean_t h)  [MI355X gfx950]
// R10: batch split 8 ways — 8 WGs/layer, each owns 8 batch rows inside a
// 16-row MFMA tile (rows 8-15 garbage, discarded; MFMA rows independent).
// Per-CU VALU (trans-dominated, 53% in R9) halves; real gate values are
// repacked across lane halves with __shfl_xor(...,32)+select so all 64
// lanes do activation work (4 h-elems/thread). A/sW LDS traffic per CU
// unchanged. Weights CU-resident as in R9 (46 frags regs, 18 LDS/wave).
// 512 thr, 8 waves, 2 waves/SIMD. Fused launch: scan0(c+1) || scan1(c).

#define T_LEN 1024
#define NB    64
#define DIN   64
#define HID   256
#define G4    1024
#define CH    128
#define NCH   (T_LEN/CH)

typedef __attribute__((ext_vector_type(8))) short  bf16x8;
typedef __attribute__((ext_vector_type(4))) float  f32x4;

__device__ __forceinline__ ushort f2b(float x) {      // fp32 -> bf16 RNE
  uint u = __float_as_uint(x);
  uint r = (u + 0x7fffu + ((u >> 16) & 1u)) >> 16;
  return (ushort)r;
}
__device__ __forceinline__ float b2f(uint u16) {      // bf16 -> fp32 exact
  return __uint_as_float(u16 << 16);
}
__device__ __forceinline__ float sigm(float x) {
  float e = __expf(-x);
  return __builtin_amdgcn_rcpf(1.f + e);
}
__device__ __forceinline__ float tanhf_fast(float x) {
  x = fmaxf(-20.f, fminf(20.f, x));                   // exact for tanh, NaN-proof
  float e = __expf(-2.f * x);
  return (1.f - e) * __builtin_amdgcn_rcpf(1.f + e);
}

// ---------------- weight convert (fp32->bf16) + bias sums -----------------
__global__ void convert_weights(const float* __restrict__ Wih0, const float* __restrict__ Whh0,
                                const float* __restrict__ Wih1, const float* __restrict__ Whh1,
                                const float* __restrict__ bih0, const float* __restrict__ bhh0,
                                const float* __restrict__ bih1, const float* __restrict__ bhh1,
                                ushort* __restrict__ Wb, float* __restrict__ bsum)
{
  int i = blockIdx.x * 256 + threadIdx.x;
  const int n0 = G4*DIN, n1 = G4*HID;
  const int total = n0 + 3*n1;                 // 851968
  if (i < total) {
    float v;
    if (i < n0)           v = Wih0[i];
    else if (i < n0+n1)   v = Whh0[i-n0];
    else if (i < n0+2*n1) v = Wih1[i-n0-n1];
    else                  v = Whh1[i-n0-2*n1];
    Wb[i] = f2b(v);
  }
  if (i < G4)        bsum[i] = bih0[i] + bhh0[i];
  else if (i < 2*G4) bsum[i] = bih1[i-G4] + bhh1[i-G4];
}

// ------------- input-projection GEMM: gx[t] = A_t @ W^T + bias -------------
// SRC=0: A = x fp32 [B][T][DIN]  (KDIM=64)
// SRC=1: A = hs0 chunk bf16 [CH][64][HID] (KDIM=256)
// grid (CH, 2): blockIdx.y picks 2 of the 4 m-tiles.
// Output gxF bf16 in MFMA-fragment order: [tloc][ct 0..63][mt 0..3][lane][r]
template<int SRC, int KDIM>
__global__ __launch_bounds__(512) void gemm_gates(
    const void* __restrict__ Asrc, const ushort* __restrict__ W,
    const float* __restrict__ bias, ushort* __restrict__ gxF, int t0)
{
  __shared__ __align__(16) char sA[64 * KDIM * 2];
  const int tid  = threadIdx.x;
  const int wave = tid >> 6, lane = tid & 63;
  const int l15 = lane & 15, lhi = lane >> 4;
  const int tloc = blockIdx.x;
  const int mt0 = blockIdx.y * 2;
  const int t = t0 + tloc;

  if (SRC == 0) {
    const float* x = (const float*)Asrc;
    int b = tid >> 3, k8 = (tid & 7) * 8;
    const float* xp = x + ((size_t)b * T_LEN + t) * DIN + k8;
    float4 v0 = *(const float4*)xp;
    float4 v1 = *(const float4*)(xp + 4);
    bf16x8 pv;
    pv[0]=(short)f2b(v0.x); pv[1]=(short)f2b(v0.y); pv[2]=(short)f2b(v0.z); pv[3]=(short)f2b(v0.w);
    pv[4]=(short)f2b(v1.x); pv[5]=(short)f2b(v1.y); pv[6]=(short)f2b(v1.z); pv[7]=(short)f2b(v1.w);
    uint bo = (uint)(b * KDIM * 2 + k8 * 2) ^ ((uint)(b & 7) << 4);
    *reinterpret_cast<bf16x8*>(&sA[bo]) = pv;
  } else {
    const ushort* hs = (const ushort*)Asrc;
    int b = tid >> 3, kb = tid & 7;
    #pragma unroll
    for (int j = 0; j < KDIM/64; ++j) {
      int k8 = (kb + j*8) * 8;
      bf16x8 v = *reinterpret_cast<const bf16x8*>(hs + ((size_t)tloc * 64 + b) * KDIM + k8);
      uint bo = (uint)(b * KDIM * 2 + k8 * 2) ^ ((uint)(b & 7) << 4);
      *reinterpret_cast<bf16x8*>(&sA[bo]) = v;
    }
  }
  __syncthreads();

  float bb[8];
  #pragma unroll
  for (int i = 0; i < 8; ++i) bb[i] = bias[(wave*8 + i)*16 + l15];

  f32x4 acc[2][8];
  #pragma unroll
  for (int m = 0; m < 2; ++m)
    #pragma unroll
    for (int i = 0; i < 8; ++i) {
      acc[m][i][0] = bb[i]; acc[m][i][1] = bb[i];
      acc[m][i][2] = bb[i]; acc[m][i][3] = bb[i];
    }

  #pragma unroll
  for (int kc = 0; kc < KDIM/32; ++kc) {
    const int koff = kc*32 + lhi*8;
    bf16x8 wf[8];
    #pragma unroll
    for (int i = 0; i < 8; ++i)
      wf[i] = *reinterpret_cast<const bf16x8*>(W + (size_t)((wave*8 + i)*16 + l15) * KDIM + koff);
    #pragma unroll
    for (int m = 0; m < 2; ++m) {
      const int row = (mt0 + m)*16 + l15;
      const uint bo = (uint)(row * KDIM * 2 + koff * 2) ^ ((uint)(row & 7) << 4);
      bf16x8 a = *reinterpret_cast<const bf16x8*>(&sA[bo]);
      #pragma unroll
      for (int i = 0; i < 8; ++i)
        acc[m][i] = __builtin_amdgcn_mfma_f32_16x16x32_bf16(a, wf[i], acc[m][i], 0, 0, 0);
    }
  }

  #pragma unroll
  for (int m = 0; m < 2; ++m)
    #pragma unroll
    for (int i = 0; i < 8; ++i) {
      const int ct = wave*8 + i;
      uint2 q;
      q.x = (uint)f2b(acc[m][i][0]) | ((uint)f2b(acc[m][i][1]) << 16);
      q.y = (uint)f2b(acc[m][i][2]) | ((uint)f2b(acc[m][i][3]) << 16);
      *reinterpret_cast<uint2*>(gxF + ((size_t)((tloc*64 + ct)*4 + (mt0+m))*64 + lane)*4) = q;
    }
}

// --------------------------- fused recurrent scan --------------------------
// Blocks [0, 8*nL1): layer1 chunk t0_l1 (grp 0..7). Rest: layer0 chunk t0_l0.
// Each grp owns batch rows [grp*8, grp*8+8) placed in MFMA rows 0..7
// (rows 8..15 garbage). 512 thr, 8 waves, 2 waves/SIMD. Wave w owns units
// [32w,32w+32) x 4 gates = 8 tiles t = gate*2 + j.
// Frags/wave: 46 in regs (kc0..4 all t; kc5 t0..5), 18 in LDS. kc-major:
// 8 A ds_reads + 64 MFMAs into acc[8]; then shfl_xor-repack so every lane
// activates 4 real (b,u) elems. sH = 8 rows x 256 u, double-buffered (2x4KB).
__global__ __launch_bounds__(512)
__attribute__((amdgpu_waves_per_eu(2, 2)))
void lstm_scan_fused(
    const ushort* __restrict__ gxF0, const ushort* __restrict__ gxF1,
    const ushort* __restrict__ Whh0, const ushort* __restrict__ Whh1,
    ushort* __restrict__ hs_out,     // L0: chunk buffer [CH][64][256] bf16
    float* __restrict__ hsum_out,    // L1: [64][256]
    ushort* __restrict__ hst0, ushort* __restrict__ hst1,
    float* __restrict__ cst0, float* __restrict__ cst1,
    float* __restrict__ hacc_state,  // L1: [8][512][4]
    int t0_l0, int t0_l1, int nL1)
{
  __shared__ __align__(16) char sW[147456];   // [8 waves][18 frags][1024B]
  __shared__ __align__(16) char sH[8192];     // h double buffer, 2 x 4KB

  const int tid = threadIdx.x;
  const int wave = tid >> 6, lane = tid & 63;
  const int l15 = lane & 15, lhi = lane >> 4;
  const int isL0 = (blockIdx.x >= (uint)(8*nL1));
  const int grp  = blockIdx.x - (isL0 ? 8*nL1 : 0);   // 0..7
  const int mt   = grp >> 1;                          // gx M-tile
  const int rsel = grp & 1;                           // row half within tile

  const ushort* gxF     = isL0 ? gxF0 : gxF1;
  const ushort* Whh     = isL0 ? Whh0 : Whh1;
  ushort*       h_state = isL0 ? hst0 : hst1;
  float*        c_state = isL0 ? cst0 : cst1;
  const int     t0      = isL0 ? t0_l0 : t0_l1;

  // ---- load weights (once): 46 frags regs + 18 frags LDS per wave ----
  bf16x8 wv[8][6];                             // sparse: 46 live entries
  #pragma unroll
  for (int t = 0; t < 8; ++t) {
    const int g = t >> 1, j = t & 1;
    const ushort* wp = Whh + (size_t)(g*256 + wave*32 + j*16 + l15) * HID;
    #pragma unroll
    for (int kc = 0; kc < 8; ++kc) {
      bf16x8 w = *reinterpret_cast<const bf16x8*>(wp + kc*32 + lhi*8);
      if (kc >= 6 || (kc == 5 && t >= 6)) {
        const int fid = (kc == 6) ? t : (kc == 7) ? (8 + t) : (16 + (t - 6));
        *reinterpret_cast<bf16x8*>(&sW[((wave*18 + fid) << 10) + lane*16]) = w;
      } else {
        wv[t][kc] = w;
      }
    }
  }

  // ---- init / restore h into buffer 0 (4KB = 8 rows x 256 u, swizzled) ----
  if (t0 == 0) {
    for (int i = tid; i < 1024; i += 512) reinterpret_cast<uint*>(sH)[i] = 0u;
  } else {
    const uint* src = reinterpret_cast<const uint*>(h_state) + grp*1024;
    for (int i = tid; i < 1024; i += 512) reinterpret_cast<uint*>(sH)[i] = src[i];
  }

  float c[4], hacc[4];
  if (t0 == 0) {
    #pragma unroll
    for (int i = 0; i < 4; ++i) { c[i] = 0.f; hacc[i] = 0.f; }
  } else {
    const float* cs = c_state + ((size_t)grp*512 + tid)*4;
    #pragma unroll
    for (int i = 0; i < 4; ++i) c[i] = cs[i];
    if (!isL0) {
      const float* ha = hacc_state + ((size_t)grp*512 + tid)*4;
      #pragma unroll
      for (int i = 0; i < 4; ++i) hacc[i] = ha[i];
    } else {
      #pragma unroll
      for (int i = 0; i < 4; ++i) hacc[i] = 0.f;
    }
  }

  // gx source lane: this WG's real rows are (rsel*8 + lhi*4 + r) of M-tile mt,
  // which live at fragment lane l15 + 16*(rsel*2 + lhi) (lhi<2; hi lanes dup)
  const int gxlane = l15 + (((rsel << 1) + (lhi & 1)) << 4);
  #define GX_LD(tl, t) (*reinterpret_cast<const uint2*>( \
      gxF + ((size_t)(((tl)*64 + ((t)>>1)*16 + wave*2 + ((t)&1))*4 + mt)*64 + gxlane)*4))
  // A-fragment read from buffer cb; rows 0..7 real, lanes l15>=8 duplicate
  #define LD_A(cb, kc) (*reinterpret_cast<const bf16x8*>(&sH[(cb)*4096 + \
      ((uint)((l15 & 7)*512 + ((kc)*32 + lhi*8)*2) ^ ((uint)(l15 & 7) << 4))]))
  // weight fragment (t, kc): regs or LDS, folded at compile time
  #define LD_W(t, kc) (((kc) >= 6 || ((kc) == 5 && (t) >= 6)) ? \
      *reinterpret_cast<const bf16x8*>(&sW[((wave*18 + \
        ((kc) == 6 ? (t) : (kc) == 7 ? (8 + (t)) : (16 + (t) - 6))) << 10) + lane*16]) \
      : wv[t][kc])

  // ---- prefetch gx for step 0 ----
  uint2 gxb[8];
  #pragma unroll
  for (int t = 0; t < 8; ++t) gxb[t] = GX_LD(0, t);

  const int jsel = lane >> 5;                  // unit half this lane activates
  const int u = wave*32 + jsel*16 + l15;       // hidden unit
  const int brow = (lhi & 1) * 4;              // local batch row base

  __syncthreads();

  int cur = 0;
  #pragma unroll 1
  for (int tloc = 0; tloc < CH; ++tloc) {
    // 1. acc init = gx (incl. bias); hi-lane rows are don't-care duplicates
    f32x4 acc[8];
    #pragma unroll
    for (int t = 0; t < 8; ++t) {
      uint2 q = gxb[t];
      acc[t][0] = b2f(q.x & 0xffffu); acc[t][1] = b2f(q.x >> 16);
      acc[t][2] = b2f(q.y & 0xffffu); acc[t][3] = b2f(q.y >> 16);
    }
    // 2. issue next step's gx loads (full step of latency cover)
    {
      const int tln = (tloc + 1) & (CH - 1);
      #pragma unroll
      for (int t = 0; t < 8; ++t) gxb[t] = GX_LD(tln, t);
    }
    // 3. kc-major MFMA block: 8 A-reads, 64 MFMAs (rows 8-15 garbage)
    #pragma unroll
    for (int kc = 0; kc < 8; ++kc) {
      bf16x8 a = LD_A(cur, kc);
      #pragma unroll
      for (int t = 0; t < 8; ++t)
        acc[t] = __builtin_amdgcn_mfma_f32_16x16x32_bf16(a, LD_W(t, kc), acc[t], 0, 0, 0);
    }
    // 4. repack: lanes<32 keep j=0 tiles, lanes>=32 receive j=1 tiles
    float pa[4][4];
    #pragma unroll
    for (int g = 0; g < 4; ++g)
      #pragma unroll
      for (int r = 0; r < 4; ++r) {
        float other = __shfl_xor(acc[2*g + 1][r], 32);
        pa[g][r] = (lane < 32) ? acc[2*g][r] : other;
      }
    // 5. activations: every lane owns 4 real elems (b=brow+r, unit u)
    #pragma unroll
    for (int r = 0; r < 4; ++r) {
      float ig = sigm(pa[0][r]);
      float fg = sigm(pa[1][r]);
      float gg = tanhf_fast(pa[2][r]);
      float og = sigm(pa[3][r]);
      float cn = __builtin_fmaf(fg, c[r], ig * gg);
      c[r] = cn;
      float h = og * tanhf_fast(cn);
      if (!isL0) hacc[r] += h;
      const int b = brow + r;
      const uint wb = (uint)(b*512 + u*2) ^ ((uint)b << 4);
      *reinterpret_cast<ushort*>(&sH[(cur ^ 1)*4096 + wb]) = f2b(h);
      if (isL0)
        hs_out[((size_t)tloc*64 + grp*8 + b)*256 + u] = f2b(h);
    }
    __syncthreads();
    cur ^= 1;
  }

  // ---- save state ----
  {
    uint* dst = reinterpret_cast<uint*>(h_state) + grp*1024;
    const uint* src = reinterpret_cast<const uint*>(&sH[cur*4096]);
    for (int i = tid; i < 1024; i += 512) dst[i] = src[i];
    float* cs = c_state + ((size_t)grp*512 + tid)*4;
    #pragma unroll
    for (int i = 0; i < 4; ++i) cs[i] = c[i];
    if (!isL0) {
      float* ha = hacc_state + ((size_t)grp*512 + tid)*4;
      #pragma unroll
      for (int i = 0; i < 4; ++i) ha[i] = hacc[i];
      #pragma unroll
      for (int r = 0; r < 4; ++r)
        hsum_out[((size_t)grp*8 + brow + r)*256 + u] = hacc[r];
    }
  }
  #undef GX_LD
  #undef LD_A
  #undef LD_W
}

// ------------------------------- final fc ---------------------------------
__global__ void fc_kernel(const float* __restrict__ hsum, const float* __restrict__ Wfc,
                          const float* __restrict__ bfc, float* __restrict__ out)
{
  int tid = threadIdx.x;
  if (tid < 640) {
    int b = tid / 10, o = tid - b*10;
    const float* hp = hsum + b*256;
    const float* wp = Wfc + o*256;
    float s = 0.f;
    #pragma unroll 8
    for (int u = 0; u < 256; ++u) s = __builtin_fmaf(hp[u], wp[u], s);
    out[tid] = s * (1.f/1024.f) + bfc[o];
  }
}

extern "C" void kernel_launch(void* const* d_in, const int* in_sizes, int n_in,
                              void* d_out, int out_size, void* d_ws, size_t ws_size,
                              hipStream_t stream)
{
  const float* x    = (const float*)d_in[0];
  const float* Wih0 = (const float*)d_in[1];
  const float* Whh0 = (const float*)d_in[2];
  const float* bih0 = (const float*)d_in[3];
  const float* bhh0 = (const float*)d_in[4];
  const float* Wih1 = (const float*)d_in[5];
  const float* Whh1 = (const float*)d_in[6];
  const float* bih1 = (const float*)d_in[7];
  const float* bhh1 = (const float*)d_in[8];
  const float* Wfc  = (const float*)d_in[9];
  const float* bfc  = (const float*)d_in[10];
  float* out = (float*)d_out;
  char* ws = (char*)d_ws;

  // ws layout (total ~42.4 MB)
  ushort* Wb    = (ushort*)(ws);                               // 1,703,936 B
  float*  bsum  = (float*)(ws + 1703936);                      // 8 KB
  ushort* gxF0  = (ushort*)(ws + 2097152);                     // 16 MB
  ushort* gxF1  = (ushort*)(ws + 2097152 + 16777216);          // 16 MB
  ushort* hs0cA = (ushort*)(ws + 2097152 + 2*16777216);        // 4 MB
  ushort* hs0cB = (ushort*)(ws + 2097152 + 2*16777216 + 4194304);
  char*   st    = ws + 2097152 + 2*16777216 + 2*4194304;
  float*  hsum  = (float*)(st);                                // 64 KB
  ushort* hst0  = (ushort*)(st + 65536);                       // 32 KB
  ushort* hst1  = (ushort*)(st + 98304);                       // 32 KB
  float*  cst0  = (float*)(st + 131072);                       // 64 KB
  float*  cst1  = (float*)(st + 196608);                       // 64 KB
  float*  hast  = (float*)(st + 262144);                       // 64 KB

  hipLaunchKernelGGL(convert_weights, dim3(3328), dim3(256), 0, stream,
                     Wih0, Whh0, Wih1, Whh1, bih0, bhh0, bih1, bhh1, Wb, bsum);

  const ushort* Whh0b = Wb + 65536;
  const ushort* Wih1b = Wb + 327680;
  const ushort* Whh1b = Wb + 589824;

  ushort* hs0c[2] = { hs0cA, hs0cB };

  // pipeline fill: layer0 chunk 0
  hipLaunchKernelGGL((gemm_gates<0,64>), dim3(CH,2), dim3(512), 0, stream,
                     (const void*)x, Wb, bsum, gxF0, 0);
  hipLaunchKernelGGL(lstm_scan_fused, dim3(8), dim3(512), 0, stream,
                     gxF0, gxF1, Whh0b, Whh1b, hs0c[0], hsum,
                     hst0, hst1, cst0, cst1, hast, 0, 0, /*nL1=*/0);

  for (int c = 0; c < NCH; ++c) {
    hipLaunchKernelGGL((gemm_gates<1,256>), dim3(CH,2), dim3(512), 0, stream,
                       (const void*)hs0c[c & 1], Wih1b, bsum + 1024, gxF1, c*CH);
    const int nL0 = (c + 1 < NCH) ? 1 : 0;
    if (nL0)
      hipLaunchKernelGGL((gemm_gates<0,64>), dim3(CH,2), dim3(512), 0, stream,
                         (const void*)x, Wb, bsum, gxF0, (c+1)*CH);
    hipLaunchKernelGGL(lstm_scan_fused, dim3(8 + 8*nL0), dim3(512), 0, stream,
                       gxF0, gxF1, Whh0b, Whh1b, hs0c[(c+1) & 1], hsum,
                       hst0, hst1, cst0, cst1, hast, (c+1)*CH, c*CH, /*nL1=*/1);
  }
  hipLaunchKernelGGL(fc_kernel, dim3(1), dim3(640), 0, stream, hsum, Wfc, bfc, out);
}

// Round 11
// 2936.824 us; speedup vs baseline: 5.2834x; 1.0585x over previous
//
#include <hip/hip_runtime.h>
#include <stdint.h>
#include <stddef.h>

// LSTM 2-layer, B=64,T=1024,D=64,H=256 -> fc(mean_t h)  [MI355X gfx950]
// R11: 16 WGs/layer x 4 batch rows (rows 4-15 of MFMA tile garbage).
// Per-SIMD MFMA is pinned at 2048 cy/step (64 MFMA/wave x 2 waves x ~16cy,
// batch=64 caps no-garbage spread at 4 WGs) — so push VALU below it:
// 2 h-elems/thread (20 trans), repack = shfl-broadcast from the 16 real
// lanes + lhi==r select. sH = 4 rows, swizzle (u*2)^(row<<5) (old
// (row&7)<<4 degenerates at 4 rows). Weights CU-resident (46 frags regs +
// 18 LDS/wave). 512 thr, 2 waves/SIMD. Fused: scan0(c+1) || scan1(c).

#define T_LEN 1024
#define NB    64
#define DIN   64
#define HID   256
#define G4    1024
#define CH    128
#define NCH   (T_LEN/CH)

typedef __attribute__((ext_vector_type(8))) short  bf16x8;
typedef __attribute__((ext_vector_type(4))) float  f32x4;

__device__ __forceinline__ ushort f2b(float x) {      // fp32 -> bf16 RNE
  uint u = __float_as_uint(x);
  uint r = (u + 0x7fffu + ((u >> 16) & 1u)) >> 16;
  return (ushort)r;
}
__device__ __forceinline__ float b2f(uint u16) {      // bf16 -> fp32 exact
  return __uint_as_float(u16 << 16);
}
__device__ __forceinline__ float sigm(float x) {
  float e = __expf(-x);
  return __builtin_amdgcn_rcpf(1.f + e);
}
__device__ __forceinline__ float tanhf_fast(float x) {
  x = fmaxf(-20.f, fminf(20.f, x));                   // exact for tanh, NaN-proof
  float e = __expf(-2.f * x);
  return (1.f - e) * __builtin_amdgcn_rcpf(1.f + e);
}

// ---------------- weight convert (fp32->bf16) + bias sums -----------------
__global__ void convert_weights(const float* __restrict__ Wih0, const float* __restrict__ Whh0,
                                const float* __restrict__ Wih1, const float* __restrict__ Whh1,
                                const float* __restrict__ bih0, const float* __restrict__ bhh0,
                                const float* __restrict__ bih1, const float* __restrict__ bhh1,
                                ushort* __restrict__ Wb, float* __restrict__ bsum)
{
  int i = blockIdx.x * 256 + threadIdx.x;
  const int n0 = G4*DIN, n1 = G4*HID;
  const int total = n0 + 3*n1;                 // 851968
  if (i < total) {
    float v;
    if (i < n0)           v = Wih0[i];
    else if (i < n0+n1)   v = Whh0[i-n0];
    else if (i < n0+2*n1) v = Wih1[i-n0-n1];
    else                  v = Whh1[i-n0-2*n1];
    Wb[i] = f2b(v);
  }
  if (i < G4)        bsum[i] = bih0[i] + bhh0[i];
  else if (i < 2*G4) bsum[i] = bih1[i-G4] + bhh1[i-G4];
}

// ------------- input-projection GEMM: gx[t] = A_t @ W^T + bias -------------
// SRC=0: A = x fp32 [B][T][DIN]  (KDIM=64)
// SRC=1: A = hs0 chunk bf16 [CH][64][HID] (KDIM=256)
// grid (CH, 2): blockIdx.y picks 2 of the 4 m-tiles.
// Output gxF bf16 in MFMA-fragment order: [tloc][ct 0..63][mt 0..3][lane][r]
template<int SRC, int KDIM>
__global__ __launch_bounds__(512) void gemm_gates(
    const void* __restrict__ Asrc, const ushort* __restrict__ W,
    const float* __restrict__ bias, ushort* __restrict__ gxF, int t0)
{
  __shared__ __align__(16) char sA[64 * KDIM * 2];
  const int tid  = threadIdx.x;
  const int wave = tid >> 6, lane = tid & 63;
  const int l15 = lane & 15, lhi = lane >> 4;
  const int tloc = blockIdx.x;
  const int mt0 = blockIdx.y * 2;
  const int t = t0 + tloc;

  if (SRC == 0) {
    const float* x = (const float*)Asrc;
    int b = tid >> 3, k8 = (tid & 7) * 8;
    const float* xp = x + ((size_t)b * T_LEN + t) * DIN + k8;
    float4 v0 = *(const float4*)xp;
    float4 v1 = *(const float4*)(xp + 4);
    bf16x8 pv;
    pv[0]=(short)f2b(v0.x); pv[1]=(short)f2b(v0.y); pv[2]=(short)f2b(v0.z); pv[3]=(short)f2b(v0.w);
    pv[4]=(short)f2b(v1.x); pv[5]=(short)f2b(v1.y); pv[6]=(short)f2b(v1.z); pv[7]=(short)f2b(v1.w);
    uint bo = (uint)(b * KDIM * 2 + k8 * 2) ^ ((uint)(b & 7) << 4);
    *reinterpret_cast<bf16x8*>(&sA[bo]) = pv;
  } else {
    const ushort* hs = (const ushort*)Asrc;
    int b = tid >> 3, kb = tid & 7;
    #pragma unroll
    for (int j = 0; j < KDIM/64; ++j) {
      int k8 = (kb + j*8) * 8;
      bf16x8 v = *reinterpret_cast<const bf16x8*>(hs + ((size_t)tloc * 64 + b) * KDIM + k8);
      uint bo = (uint)(b * KDIM * 2 + k8 * 2) ^ ((uint)(b & 7) << 4);
      *reinterpret_cast<bf16x8*>(&sA[bo]) = v;
    }
  }
  __syncthreads();

  float bb[8];
  #pragma unroll
  for (int i = 0; i < 8; ++i) bb[i] = bias[(wave*8 + i)*16 + l15];

  f32x4 acc[2][8];
  #pragma unroll
  for (int m = 0; m < 2; ++m)
    #pragma unroll
    for (int i = 0; i < 8; ++i) {
      acc[m][i][0] = bb[i]; acc[m][i][1] = bb[i];
      acc[m][i][2] = bb[i]; acc[m][i][3] = bb[i];
    }

  #pragma unroll
  for (int kc = 0; kc < KDIM/32; ++kc) {
    const int koff = kc*32 + lhi*8;
    bf16x8 wf[8];
    #pragma unroll
    for (int i = 0; i < 8; ++i)
      wf[i] = *reinterpret_cast<const bf16x8*>(W + (size_t)((wave*8 + i)*16 + l15) * KDIM + koff);
    #pragma unroll
    for (int m = 0; m < 2; ++m) {
      const int row = (mt0 + m)*16 + l15;
      const uint bo = (uint)(row * KDIM * 2 + koff * 2) ^ ((uint)(row & 7) << 4);
      bf16x8 a = *reinterpret_cast<const bf16x8*>(&sA[bo]);
      #pragma unroll
      for (int i = 0; i < 8; ++i)
        acc[m][i] = __builtin_amdgcn_mfma_f32_16x16x32_bf16(a, wf[i], acc[m][i], 0, 0, 0);
    }
  }

  #pragma unroll
  for (int m = 0; m < 2; ++m)
    #pragma unroll
    for (int i = 0; i < 8; ++i) {
      const int ct = wave*8 + i;
      uint2 q;
      q.x = (uint)f2b(acc[m][i][0]) | ((uint)f2b(acc[m][i][1]) << 16);
      q.y = (uint)f2b(acc[m][i][2]) | ((uint)f2b(acc[m][i][3]) << 16);
      *reinterpret_cast<uint2*>(gxF + ((size_t)((tloc*64 + ct)*4 + (mt0+m))*64 + lane)*4) = q;
    }
}

// --------------------------- fused recurrent scan --------------------------
// Blocks [0, 16*nL1): layer1 chunk t0_l1 (grp 0..15). Rest: layer0 t0_l0.
// Each grp owns batch rows [grp*4, grp*4+4) in MFMA rows 0..3 (4..15 junk).
// 512 thr, 8 waves, 2 waves/SIMD. Wave w owns units [32w,32w+32) x 4 gates
// = 8 tiles t = gate*2 + j. Frags/wave: 46 regs + 18 LDS. kc-major: 8 A
// ds_reads + 64 MFMAs into acc[8]; repack = __shfl(acc,l15) broadcast from
// the 16 real lanes + (lhi==r) select -> every lane activates 2 elems
// (row lhi, units wave*32+{0,16}+l15). sH 4 rows, dbuf 2x2KB, swizzle
// (u*2)^(row<<5).
__global__ __launch_bounds__(512)
__attribute__((amdgpu_waves_per_eu(2, 2)))
void lstm_scan_fused(
    const ushort* __restrict__ gxF0, const ushort* __restrict__ gxF1,
    const ushort* __restrict__ Whh0, const ushort* __restrict__ Whh1,
    ushort* __restrict__ hs_out,     // L0: chunk buffer [CH][64][256] bf16
    float* __restrict__ hsum_out,    // L1: [64][256]
    ushort* __restrict__ hst0, ushort* __restrict__ hst1,
    float* __restrict__ cst0, float* __restrict__ cst1,
    float* __restrict__ hacc_state,  // L1: [16][512][2]
    int t0_l0, int t0_l1, int nL1)
{
  __shared__ __align__(16) char sW[147456];   // [8 waves][18 frags][1024B]
  __shared__ __align__(16) char sH[4096];     // h double buffer, 2 x 2KB

  const int tid = threadIdx.x;
  const int wave = tid >> 6, lane = tid & 63;
  const int l15 = lane & 15, lhi = lane >> 4;
  const int isL0 = (blockIdx.x >= (uint)(16*nL1));
  const int grp  = blockIdx.x - (isL0 ? 16*nL1 : 0);  // 0..15
  const int mt   = grp >> 2;                          // gx M-tile
  const int q4   = grp & 3;                           // row quarter in tile

  const ushort* gxF     = isL0 ? gxF0 : gxF1;
  const ushort* Whh     = isL0 ? Whh0 : Whh1;
  ushort*       h_state = isL0 ? hst0 : hst1;
  float*        c_state = isL0 ? cst0 : cst1;
  const int     t0      = isL0 ? t0_l0 : t0_l1;

  // ---- load weights (once): 46 frags regs + 18 frags LDS per wave ----
  bf16x8 wv[8][6];                             // sparse: 46 live entries
  #pragma unroll
  for (int t = 0; t < 8; ++t) {
    const int g = t >> 1, j = t & 1;
    const ushort* wp = Whh + (size_t)(g*256 + wave*32 + j*16 + l15) * HID;
    #pragma unroll
    for (int kc = 0; kc < 8; ++kc) {
      bf16x8 w = *reinterpret_cast<const bf16x8*>(wp + kc*32 + lhi*8);
      if (kc >= 6 || (kc == 5 && t >= 6)) {
        const int fid = (kc == 6) ? t : (kc == 7) ? (8 + t) : (16 + (t - 6));
        *reinterpret_cast<bf16x8*>(&sW[((wave*18 + fid) << 10) + lane*16]) = w;
      } else {
        wv[t][kc] = w;
      }
    }
  }

  // ---- init / restore h into buffer 0 (2KB = 4 rows x 256 u, swizzled) ----
  if (t0 == 0) {
    if (tid < 512) reinterpret_cast<uint*>(sH)[tid] = 0u;
  } else {
    const uint* src = reinterpret_cast<const uint*>(h_state) + grp*512;
    if (tid < 512) reinterpret_cast<uint*>(sH)[tid] = src[tid];
  }

  float c[2], hacc[2];
  if (t0 == 0) {
    c[0] = c[1] = 0.f; hacc[0] = hacc[1] = 0.f;
  } else {
    const float* cs = c_state + ((size_t)grp*512 + tid)*2;
    c[0] = cs[0]; c[1] = cs[1];
    if (!isL0) {
      const float* ha = hacc_state + ((size_t)grp*512 + tid)*2;
      hacc[0] = ha[0]; hacc[1] = ha[1];
    } else {
      hacc[0] = hacc[1] = 0.f;
    }
  }

  // gx: this WG's rows q4*4..q4*4+3 of M-tile mt live at fragment lane
  // q4*16 + l15, regs 0..3 — all lane groups load the same 16 addresses.
  const int gxlane = (q4 << 4) + l15;
  #define GX_LD(tl, t) (*reinterpret_cast<const uint2*>( \
      gxF + ((size_t)(((tl)*64 + ((t)>>1)*16 + wave*2 + ((t)&1))*4 + mt)*64 + gxlane)*4))
  // A-fragment from buffer cb: row = l15&3 (lanes 4-15 duplicate), swizzled
  #define LD_A(cb, kc) (*reinterpret_cast<const bf16x8*>(&sH[(cb)*2048 + \
      (uint)((l15 & 3)*512) + (((uint)((kc)*64 + lhi*16)) ^ ((uint)(l15 & 3) << 5))]))
  // weight fragment (t, kc): regs or LDS, folded at compile time
  #define LD_W(t, kc) (((kc) >= 6 || ((kc) == 5 && (t) >= 6)) ? \
      *reinterpret_cast<const bf16x8*>(&sW[((wave*18 + \
        ((kc) == 6 ? (t) : (kc) == 7 ? (8 + (t)) : (16 + (t) - 6))) << 10) + lane*16]) \
      : wv[t][kc])

  // ---- prefetch gx for step 0 ----
  uint2 gxb[8];
  #pragma unroll
  for (int t = 0; t < 8; ++t) gxb[t] = GX_LD(0, t);

  __syncthreads();

  int cur = 0;
  #pragma unroll 1
  for (int tloc = 0; tloc < CH; ++tloc) {
    // 1. acc init = gx (incl. bias); rows 4-15 are don't-care dups
    f32x4 acc[8];
    #pragma unroll
    for (int t = 0; t < 8; ++t) {
      uint2 qv = gxb[t];
      acc[t][0] = b2f(qv.x & 0xffffu); acc[t][1] = b2f(qv.x >> 16);
      acc[t][2] = b2f(qv.y & 0xffffu); acc[t][3] = b2f(qv.y >> 16);
    }
    // 2. issue next step's gx loads (full step of latency cover)
    {
      const int tln = (tloc + 1) & (CH - 1);
      #pragma unroll
      for (int t = 0; t < 8; ++t) gxb[t] = GX_LD(tln, t);
    }
    // 3. kc-major MFMA block: 8 A-reads, 64 MFMAs (rows 4-15 garbage)
    #pragma unroll
    for (int kc = 0; kc < 8; ++kc) {
      bf16x8 a = LD_A(cur, kc);
      #pragma unroll
      for (int t = 0; t < 8; ++t)
        acc[t] = __builtin_amdgcn_mfma_f32_16x16x32_bf16(a, LD_W(t, kc), acc[t], 0, 0, 0);
    }
    // 4. repack: broadcast real values (lanes 0-15, regs r=row) to lane
    //    groups: lane (lhi,l15) takes reg r==lhi from source lane l15.
    float pa[4][2];
    #pragma unroll
    for (int g = 0; g < 4; ++g)
      #pragma unroll
      for (int j = 0; j < 2; ++j) {
        float v = 0.f;
        #pragma unroll
        for (int r = 0; r < 4; ++r) {
          float sh = __shfl(acc[2*g + j][r], l15);
          v = (lhi == r) ? sh : v;
        }
        pa[g][j] = v;
      }
    // 5. activations: lane owns (row=lhi, units wave*32+{0,16}+l15)
    #pragma unroll
    for (int j = 0; j < 2; ++j) {
      float ig = sigm(pa[0][j]);
      float fg = sigm(pa[1][j]);
      float gg = tanhf_fast(pa[2][j]);
      float og = sigm(pa[3][j]);
      float cn = __builtin_fmaf(fg, c[j], ig * gg);
      c[j] = cn;
      float h = og * tanhf_fast(cn);
      if (!isL0) hacc[j] += h;
      const int u = wave*32 + j*16 + l15;
      const uint wb = (uint)(lhi*512) + (((uint)(u*2)) ^ ((uint)lhi << 5));
      *reinterpret_cast<ushort*>(&sH[(cur ^ 1)*2048 + wb]) = f2b(h);
      if (isL0)
        hs_out[((size_t)tloc*64 + grp*4 + lhi)*256 + u] = f2b(h);
    }
    __syncthreads();
    cur ^= 1;
  }

  // ---- save state ----
  {
    uint* dst = reinterpret_cast<uint*>(h_state) + grp*512;
    const uint* src = reinterpret_cast<const uint*>(&sH[cur*2048]);
    if (tid < 512) dst[tid] = src[tid];
    float* cs = c_state + ((size_t)grp*512 + tid)*2;
    cs[0] = c[0]; cs[1] = c[1];
    if (!isL0) {
      float* ha = hacc_state + ((size_t)grp*512 + tid)*2;
      ha[0] = hacc[0]; ha[1] = hacc[1];
      #pragma unroll
      for (int j = 0; j < 2; ++j) {
        const int u = wave*32 + j*16 + l15;
        hsum_out[((size_t)grp*4 + lhi)*256 + u] = hacc[j];
      }
    }
  }
  #undef GX_LD
  #undef LD_A
  #undef LD_W
}

// ------------------------------- final fc ---------------------------------
__global__ void fc_kernel(const float* __restrict__ hsum, const float* __restrict__ Wfc,
                          const float* __restrict__ bfc, float* __restrict__ out)
{
  int tid = threadIdx.x;
  if (tid < 640) {
    int b = tid / 10, o = tid - b*10;
    const float* hp = hsum + b*256;
    const float* wp = Wfc + o*256;
    float s = 0.f;
    #pragma unroll 8
    for (int u = 0; u < 256; ++u) s = __builtin_fmaf(hp[u], wp[u], s);
    out[tid] = s * (1.f/1024.f) + bfc[o];
  }
}

extern "C" void kernel_launch(void* const* d_in, const int* in_sizes, int n_in,
                              void* d_out, int out_size, void* d_ws, size_t ws_size,
                              hipStream_t stream)
{
  const float* x    = (const float*)d_in[0];
  const float* Wih0 = (const float*)d_in[1];
  const float* Whh0 = (const float*)d_in[2];
  const float* bih0 = (const float*)d_in[3];
  const float* bhh0 = (const float*)d_in[4];
  const float* Wih1 = (const float*)d_in[5];
  const float* Whh1 = (const float*)d_in[6];
  const float* bih1 = (const float*)d_in[7];
  const float* bhh1 = (const float*)d_in[8];
  const float* Wfc  = (const float*)d_in[9];
  const float* bfc  = (const float*)d_in[10];
  float* out = (float*)d_out;
  char* ws = (char*)d_ws;

  // ws layout (total ~42.4 MB)
  ushort* Wb    = (ushort*)(ws);                               // 1,703,936 B
  float*  bsum  = (float*)(ws + 1703936);                      // 8 KB
  ushort* gxF0  = (ushort*)(ws + 2097152);                     // 16 MB
  ushort* gxF1  = (ushort*)(ws + 2097152 + 16777216);          // 16 MB
  ushort* hs0cA = (ushort*)(ws + 2097152 + 2*16777216);        // 4 MB
  ushort* hs0cB = (ushort*)(ws + 2097152 + 2*16777216 + 4194304);
  char*   st    = ws + 2097152 + 2*16777216 + 2*4194304;
  float*  hsum  = (float*)(st);                                // 64 KB
  ushort* hst0  = (ushort*)(st + 65536);                       // 32 KB
  ushort* hst1  = (ushort*)(st + 98304);                       // 32 KB
  float*  cst0  = (float*)(st + 131072);                       // 64 KB
  float*  cst1  = (float*)(st + 196608);                       // 64 KB
  float*  hast  = (float*)(st + 262144);                       // 64 KB

  hipLaunchKernelGGL(convert_weights, dim3(3328), dim3(256), 0, stream,
                     Wih0, Whh0, Wih1, Whh1, bih0, bhh0, bih1, bhh1, Wb, bsum);

  const ushort* Whh0b = Wb + 65536;
  const ushort* Wih1b = Wb + 327680;
  const ushort* Whh1b = Wb + 589824;

  ushort* hs0c[2] = { hs0cA, hs0cB };

  // pipeline fill: layer0 chunk 0
  hipLaunchKernelGGL((gemm_gates<0,64>), dim3(CH,2), dim3(512), 0, stream,
                     (const void*)x, Wb, bsum, gxF0, 0);
  hipLaunchKernelGGL(lstm_scan_fused, dim3(16), dim3(512), 0, stream,
                     gxF0, gxF1, Whh0b, Whh1b, hs0c[0], hsum,
                     hst0, hst1, cst0, cst1, hast, 0, 0, /*nL1=*/0);

  for (int c = 0; c < NCH; ++c) {
    hipLaunchKernelGGL((gemm_gates<1,256>), dim3(CH,2), dim3(512), 0, stream,
                       (const void*)hs0c[c & 1], Wih1b, bsum + 1024, gxF1, c*CH);
    const int nL0 = (c + 1 < NCH) ? 1 : 0;
    if (nL0)
      hipLaunchKernelGGL((gemm_gates<0,64>), dim3(CH,2), dim3(512), 0, stream,
                         (const void*)x, Wb, bsum, gxF0, (c+1)*CH);
    hipLaunchKernelGGL(lstm_scan_fused, dim3(16 + 16*nL0), dim3(512), 0, stream,
                       gxF0, gxF1, Whh0b, Whh1b, hs0c[(c+1) & 1], hsum,
                       hst0, hst1, cst0, cst1, hast, (c+1)*CH, c*CH, /*nL1=*/1);
  }
  hipLaunchKernelGGL(fc_kernel, dim3(1), dim3(640), 0, stream, hsum, Wfc, bfc, out);
}